// Round 7
// baseline (502.557 us; speedup 1.0000x reference)
//
#include <hip/hip_runtime.h>
#include <math.h>

#define F_ 48
#define C_ 128
#define HW 16384
#define SCALE_C 0.999f
#define TPB 256

typedef __attribute__((ext_vector_type(8))) short short8;
typedef __attribute__((ext_vector_type(4))) float floatx4;
typedef __attribute__((ext_vector_type(2))) float v2;
typedef __attribute__((ext_vector_type(2))) unsigned int uint2v;

// ---- ws layout ----
// ushort region:
//   P1 frags: [b(2)][hl(2)][mt(12)][ks(4)][lane(64)][j(8)]  = 98304 ushorts
//   P2 frags: [b(2)][hl(2)][cmt(8)][ks(6)][lane(64)][j(8)]  = 98304 ushorts
// float region at float offset 98304:
#define P1_U 0
#define P2_U 98304
#define QEQN_F 98304              // [48][32] pair-interleaved
#define MISC_F (QEQN_F + 1536)    // eps_e, invden
#define XS 136
#define AS 200
#define QS 36

__device__ __forceinline__ unsigned short f2bf(float f) {     // RTNE
    unsigned u = __float_as_uint(f);
    unsigned r = u + 0x7fffu + ((u >> 16) & 1u);
    return (unsigned short)(r >> 16);
}
__device__ __forceinline__ float bf2f(unsigned short h) {
    return __uint_as_float(((unsigned)h) << 16);
}

// ---------------- merged setup (unchanged from R6 — proven clean) ----------------
__global__ void setup_all(const float* __restrict__ sigma,
                          const float* __restrict__ Qp,
                          const float* __restrict__ taus_p,
                          const float* __restrict__ lamb,
                          const float* __restrict__ eps_om,
                          const float* __restrict__ mw1, const float* __restrict__ mb1,
                          const float* __restrict__ mw2, const float* __restrict__ mb2,
                          const float* __restrict__ mw3, const float* __restrict__ mb3,
                          const float* __restrict__ Wf,
                          float* __restrict__ wsf)
{
    __shared__ float sInv[2][F_];
    __shared__ float sLam[2][F_];
    const int tid = threadIdx.x;
    unsigned short* wsu = (unsigned short*)wsf;

    if (tid >= 48 && tid < 50) {
        const int b = tid - 48;
        float lamb_e = expf(lamb[0]);
        float sg = sigma[b];
        float t = sg * 20.0f - 2.0f;
        float h1[F_], h2[F_];
        for (int j = 0; j < F_; ++j) h1[j] = fmaxf(t * mw1[j] + mb1[j], 0.0f);
        for (int j = 0; j < F_; ++j) {
            float s = mb2[j];
            for (int k = 0; k < F_; ++k) s += h1[k] * mw2[k * F_ + j];
            h2[j] = fmaxf(s, 0.0f);
        }
        for (int j = 0; j < F_; ++j) {
            float s = mb3[j];
            for (int k = 0; k < F_; ++k) s += h2[k] * mw3[k * F_ + j];
            float sc = fmaxf(s * 0.05f + sg, 0.0f) + 1e-9f;
            sInv[b][j] = 1.0f / sc;
            sLam[b][j] = lamb_e * sc;
        }
    }
    if (blockIdx.x == 0) {
        if (tid < F_) {
            const int f = tid;
            float Qm[4][4];
            for (int g = 0; g < 4; ++g) {
                float s = 0.f;
                for (int l = 0; l < 4; ++l) s += fabsf(Qp[f * 16 + g * 4 + l]);
                float d = fmaxf(s, 1.0f);
                for (int l = 0; l < 4; ++l) Qm[g][l] = Qp[f * 16 + g * 4 + l] / d;
            }
            double A[4][4];
            for (int i = 0; i < 4; ++i)
                for (int j = 0; j < 4; ++j) {
                    double s = 0.0;
                    for (int g = 0; g < 4; ++g) s += (double)Qm[g][i] * (double)Qm[g][j];
                    A[i][j] = s;
                }
            double M[4][4];
            for (int i = 0; i < 4; ++i) for (int j = 0; j < 4; ++j) M[i][j] = A[i][j];
            for (int it = 0; it < 30; ++it) {
                double T[4][4]; double mx = 0.0;
                for (int i = 0; i < 4; ++i)
                    for (int j = 0; j < 4; ++j) {
                        double s = 0.0;
                        for (int k = 0; k < 4; ++k) s += M[i][k] * M[k][j];
                        T[i][j] = s;
                        double a = fabs(s); if (a > mx) mx = a;
                    }
                if (mx < 1e-300) break;
                double inv = 1.0 / mx;
                for (int i = 0; i < 4; ++i) for (int j = 0; j < 4; ++j) M[i][j] = T[i][j] * inv;
            }
            int jb = 0; double bn = -1.0;
            for (int j = 0; j < 4; ++j) {
                double nn = 0.0;
                for (int i = 0; i < 4; ++i) nn += M[i][j] * M[i][j];
                if (nn > bn) { bn = nn; jb = j; }
            }
            double v[4]; for (int i = 0; i < 4; ++i) v[i] = M[i][jb];
            double Av[4];
            for (int i = 0; i < 4; ++i) {
                double s = 0.0;
                for (int j = 0; j < 4; ++j) s += A[i][j] * v[j];
                Av[i] = s;
            }
            double vv = 0.0, vav = 0.0;
            for (int i = 0; i < 4; ++i) { vv += v[i] * v[i]; vav += v[i] * Av[i]; }
            float lamf = (float)((vv > 0.0) ? (vav / vv) : 0.0);
            float tau = expf(fmaxf(taus_p[f], 0.0f));
            float qsv = SCALE_C / tau;
            for (int g = 0; g < 4; ++g) {
                for (int l = 0; l < 4; ++l)
                    wsf[QEQN_F + f * 32 + 4 * g + l] = qsv * Qm[l][g] / lamf;
                for (int l = 0; l < 4; ++l)
                    wsf[QEQN_F + f * 32 + 16 + 4 * g + l] = SCALE_C * Qm[g][l];
            }
        }
        if (tid == 50) {
            float lamb_e = expf(lamb[0]);
            float eps_e = expf(eps_om[0]);
            wsf[MISC_F + 0] = eps_e;
            wsf[MISC_F + 1] = 1.0f / (1.0f + lamb_e * (1.0f + eps_e));
        }
    }
    __syncthreads();

    for (int i = blockIdx.x * TPB + tid; i < 49152; i += gridDim.x * TPB) {
        if (i < 24576) {
            int j = i & 7, lane = (i >> 3) & 63;
            int t = i >> 9;
            int ks = t & 3, mt = t >> 2;
            int m = lane & 15, q = lane >> 4;
            int r = mt * 16 + m;
            int c = ks * 32 + q * 8 + j;
            int f = r >> 2, g = r & 3;
            float w = Wf[(g * F_ + f) * C_ + c];
#pragma unroll
            for (int b = 0; b < 2; ++b) {
                float v = w * sInv[b][f];
                unsigned short h = (unsigned short)(__float_as_uint(v) >> 16);
                float lo = v - bf2f(h);
                unsigned short l = (unsigned short)(__float_as_uint(lo) >> 16);
                wsu[P1_U + ((((b * 2 + 0) * 12 + mt) * 4 + ks) * 64 + lane) * 8 + j] = h;
                wsu[P1_U + ((((b * 2 + 1) * 12 + mt) * 4 + ks) * 64 + lane) * 8 + j] = l;
            }
        } else {
            int ii = i - 24576;
            int j = ii & 7, lane = (ii >> 3) & 63;
            int t = ii >> 9;
            int ks = t % 6, cmt = t / 6;
            int m = lane & 15, q = lane >> 4;
            int cch = cmt * 16 + m;
            int r = ks * 32 + q * 8 + j;
            int f = r >> 2, g = r & 3;
            float w = Wf[(g * F_ + f) * C_ + cch];
#pragma unroll
            for (int b = 0; b < 2; ++b) {
                float v = w * sLam[b][f];
                unsigned short h = (unsigned short)(__float_as_uint(v) >> 16);
                float lo = v - bf2f(h);
                unsigned short l = (unsigned short)(__float_as_uint(lo) >> 16);
                wsu[P2_U + ((((b * 2 + 0) * 8 + cmt) * 6 + ks) * 64 + lane) * 8 + j] = h;
                wsu[P2_U + ((((b * 2 + 1) * 8 + cmt) * 6 + ks) * 64 + lane) * 8 + j] = l;
            }
        }
    }
}

// proj4 on named scalars (no arrays)
#define PROJ4(v0, v1, v2_, v3, o0, o1, o2, o3)                                  \
    {                                                                           \
        float a0 = fabsf(v0), a1 = fabsf(v1), a2 = fabsf(v2_), a3 = fabsf(v3);  \
        float sum = a0 + a1 + a2 + a3;                                          \
        float t0 = fmaxf(a0, a1), u0 = fminf(a0, a1);                           \
        float t1 = fmaxf(a2, a3), u1 = fminf(a2, a3);                           \
        float s0 = fmaxf(t0, t1), m0 = fminf(t0, t1);                           \
        float m1 = fmaxf(u0, u1), s3 = fminf(u0, u1);                           \
        float s1 = fmaxf(m1, m0), s2 = fminf(m1, m0);                           \
        float c2 = s0 + s1, c3 = c2 + s2, c4 = c3 + s3;                         \
        float th = s0 - 1.0f, rh = 1.0f;                                        \
        if (s1 * 2.0f > c2 - 1.0f) { th = c2 - 1.0f; rh = 2.0f; }               \
        if (s2 * 3.0f > c3 - 1.0f) { th = c3 - 1.0f; rh = 3.0f; }               \
        if (s3 * 4.0f > c4 - 1.0f) { th = c4 - 1.0f; rh = 4.0f; }               \
        float theta = fmaxf(th / rh, 0.0f);                                     \
        bool inside = (sum <= 1.0f);                                            \
        o0 = inside ? v0 : copysignf(fmaxf(a0 - theta, 0.0f), v0);              \
        o1 = inside ? v1 : copysignf(fmaxf(a1 - theta, 0.0f), v1);              \
        o2 = inside ? v2_ : copysignf(fmaxf(a2 - theta, 0.0f), v2_);            \
        o3 = inside ? v3 : copysignf(fmaxf(a3 - theta, 0.0f), v3);              \
    }

__device__ __forceinline__ v2 fma2(v2 a, v2 b, v2 c) {
    return __builtin_elementwise_fma(a, b, c);
}

// ---------------- main ----------------
__global__ __launch_bounds__(TPB, 4) void mfoe_main(
    const float* __restrict__ xnoisy,
    const float* __restrict__ wsf,
    float* __restrict__ out,
    const int* __restrict__ n_iter_p)
{
    __shared__ __align__(16) unsigned short sXH[32 * XS];
    __shared__ __align__(16) unsigned short sXL[32 * XS];
    __shared__ __align__(16) unsigned short sACT[32 * AS];
    __shared__ __align__(16) float sQ[F_ * QS];

    const int tid = threadIdx.x;
    const int lane = tid & 63;
    const int wv = __builtin_amdgcn_readfirstlane(tid >> 6);
    const int n = lane & 15;
    const int q = lane >> 4;
    const int blk = blockIdx.x;
    const int b = blk >> 9;
    const int pix0 = (blk & 511) << 5;

    const float* __restrict__ xin = xnoisy + b * (C_ * HW) + pix0;
    float* __restrict__ oimg = out + b * (C_ * HW) + pix0;
    const unsigned short* __restrict__ wsu = (const unsigned short*)wsf;
    const int niter = *n_iter_p;

    if (niter == 0) {
        for (int i = tid; i < C_ * 32; i += TPB) {
            int p = i & 31, c = i >> 5;
            oimg[c * HW + p] = xin[c * HW + p];
        }
        return;
    }

    // stage x -> LDS bf16 hi/lo (coalesced)
    for (int i = tid; i < C_ * 32; i += TPB) {
        int p = i & 31, c = i >> 5;
        float v = xin[c * HW + p];
        unsigned short h = (unsigned short)(__float_as_uint(v) >> 16);
        float lo = v - bf2f(h);
        sXH[p * XS + c] = h;
        sXL[p * XS + c] = (unsigned short)(__float_as_uint(lo) >> 16);
    }
    // stage activation params
    for (int i = tid; i < F_ * 32; i += TPB)
        sQ[(i >> 5) * QS + (i & 31)] = wsf[QEQN_F + i];

    // x_noisy preload, all-constant indices: xn_<cl><nt> as v2 pairs
    const int p0 = n, p1 = 16 + n;
    const int cb0 = (wv * 2 + 0) * 16 + q * 4;
    const int cb1 = (wv * 2 + 1) * 16 + q * 4;
    v2 xn00a = {xin[(cb0 + 0) * HW + p0], xin[(cb0 + 1) * HW + p0]};
    v2 xn00b = {xin[(cb0 + 2) * HW + p0], xin[(cb0 + 3) * HW + p0]};
    v2 xn01a = {xin[(cb0 + 0) * HW + p1], xin[(cb0 + 1) * HW + p1]};
    v2 xn01b = {xin[(cb0 + 2) * HW + p1], xin[(cb0 + 3) * HW + p1]};
    v2 xn10a = {xin[(cb1 + 0) * HW + p0], xin[(cb1 + 1) * HW + p0]};
    v2 xn10b = {xin[(cb1 + 2) * HW + p0], xin[(cb1 + 3) * HW + p0]};
    v2 xn11a = {xin[(cb1 + 0) * HW + p1], xin[(cb1 + 1) * HW + p1]};
    v2 xn11b = {xin[(cb1 + 2) * HW + p1], xin[(cb1 + 3) * HW + p1]};

    const float eps_e = wsf[MISC_F + 0];
    const float invden = wsf[MISC_F + 1];

    for (int it = 0; it < niter; ++it) {
        __syncthreads();   // x ready (and sQ on iter 0)

        // ---- pass 1: wave owns 3 m-tiles; frags+params loaded once per mt
#pragma unroll 1
        for (int jj = 0; jj < 3; ++jj) {
            const int mt = wv * 3 + jj;
            const short8* aHp = (const short8*)(wsu + P1_U + (((b * 2 + 0) * 12 + mt) * 4) * 512 + lane * 8);
            const short8* aLp = (const short8*)(wsu + P1_U + (((b * 2 + 1) * 12 + mt) * 4) * 512 + lane * 8);
            floatx4 accA = (floatx4){0.f, 0.f, 0.f, 0.f};
            floatx4 accB = (floatx4){0.f, 0.f, 0.f, 0.f};
#pragma unroll
            for (int ks = 0; ks < 4; ++ks) {
                short8 aH = aHp[ks * 64];
                short8 aL = aLp[ks * 64];
                short8 bH0 = *(const short8*)&sXH[p0 * XS + ks * 32 + q * 8];
                short8 bL0 = *(const short8*)&sXL[p0 * XS + ks * 32 + q * 8];
                short8 bH1 = *(const short8*)&sXH[p1 * XS + ks * 32 + q * 8];
                short8 bL1 = *(const short8*)&sXL[p1 * XS + ks * 32 + q * 8];
                accA = __builtin_amdgcn_mfma_f32_16x16x32_bf16(aH, bH0, accA, 0, 0, 0);
                accB = __builtin_amdgcn_mfma_f32_16x16x32_bf16(aH, bH1, accB, 0, 0, 0);
                accA = __builtin_amdgcn_mfma_f32_16x16x32_bf16(aH, bL0, accA, 0, 0, 0);
                accB = __builtin_amdgcn_mfma_f32_16x16x32_bf16(aH, bL1, accB, 0, 0, 0);
                accA = __builtin_amdgcn_mfma_f32_16x16x32_bf16(aL, bH0, accA, 0, 0, 0);
                accB = __builtin_amdgcn_mfma_f32_16x16x32_bf16(aL, bH1, accB, 0, 0, 0);
            }
            const int f = mt * 4 + q;
            floatx4 qf0 = *(const floatx4*)&sQ[f * QS + 0];
            floatx4 qf1 = *(const floatx4*)&sQ[f * QS + 4];
            floatx4 qf2 = *(const floatx4*)&sQ[f * QS + 8];
            floatx4 qf3 = *(const floatx4*)&sQ[f * QS + 12];
            floatx4 qf4 = *(const floatx4*)&sQ[f * QS + 16];
            floatx4 qf5 = *(const floatx4*)&sQ[f * QS + 20];
            floatx4 qf6 = *(const floatx4*)&sQ[f * QS + 24];
            floatx4 qf7 = *(const floatx4*)&sQ[f * QS + 28];
#pragma unroll
            for (int nt = 0; nt < 2; ++nt) {
                const int p = nt ? p1 : p0;
                floatx4 acc = nt ? accB : accA;
                float v0 = acc[0], v1 = acc[1], vv2 = acc[2], v3 = acc[3];
                float pv0, pv1, pv2, pv3;
                PROJ4(v0, v1, vv2, v3, pv0, pv1, pv2, pv3);
                v2 y01 = qf0.xy * v0, y23 = qf0.zw * v0;
                y01 = fma2(qf1.xy, (v2){v1, v1}, y01);  y23 = fma2(qf1.zw, (v2){v1, v1}, y23);
                y01 = fma2(qf2.xy, (v2){vv2, vv2}, y01); y23 = fma2(qf2.zw, (v2){vv2, vv2}, y23);
                y01 = fma2(qf3.xy, (v2){v3, v3}, y01);  y23 = fma2(qf3.zw, (v2){v3, v3}, y23);
                float y0 = y01.x, y1 = y01.y, y2 = y23.x, y3 = y23.y;
                float py0, py1, py2, py3;
                PROJ4(y0, y1, y2, y3, py0, py1, py2, py3);
                float m20 = fmaf(eps_e, y0, py0);
                float m21 = fmaf(eps_e, y1, py1);
                float m22 = fmaf(eps_e, y2, py2);
                float m23 = fmaf(eps_e, y3, py3);
                v2 g01 = qf4.xy * m20, g23 = qf4.zw * m20;
                g01 = fma2(qf5.xy, (v2){m21, m21}, g01); g23 = fma2(qf5.zw, (v2){m21, m21}, g23);
                g01 = fma2(qf6.xy, (v2){m22, m22}, g01); g23 = fma2(qf6.zw, (v2){m22, m22}, g23);
                g01 = fma2(qf7.xy, (v2){m23, m23}, g01); g23 = fma2(qf7.zw, (v2){m23, m23}, g23);
                float a0 = fmaf(eps_e, v0, pv0) - g01.x;
                float a1 = fmaf(eps_e, v1, pv1) - g01.y;
                float a2 = fmaf(eps_e, vv2, pv2) - g23.x;
                float a3 = fmaf(eps_e, v3, pv3) - g23.y;
                unsigned pk0 = ((unsigned)f2bf(a1) << 16) | f2bf(a0);
                unsigned pk1 = ((unsigned)f2bf(a3) << 16) | f2bf(a2);
                *(uint2v*)&sACT[p * AS + mt * 16 + q * 4] = (uint2v){pk0, pk1};
            }
        }
        __syncthreads();   // act ready; all pass-1 x reads done

        // ---- pass 2: named accumulators, cl fully unrolled (no runtime-indexed arrays)
        floatx4 acc2_00 = (floatx4){0.f, 0.f, 0.f, 0.f};
        floatx4 acc2_01 = (floatx4){0.f, 0.f, 0.f, 0.f};
        floatx4 acc2_10 = (floatx4){0.f, 0.f, 0.f, 0.f};
        floatx4 acc2_11 = (floatx4){0.f, 0.f, 0.f, 0.f};
        {
            const int cmt = wv * 2 + 0;
            const short8* a2H = (const short8*)(wsu + P2_U + (((b * 2 + 0) * 8 + cmt) * 6) * 512 + lane * 8);
            const short8* a2L = (const short8*)(wsu + P2_U + (((b * 2 + 1) * 8 + cmt) * 6) * 512 + lane * 8);
#pragma unroll
            for (int ks = 0; ks < 6; ++ks) {
                short8 aH = a2H[ks * 64];
                short8 aL = a2L[ks * 64];
                short8 bA0 = *(const short8*)&sACT[p0 * AS + ks * 32 + q * 8];
                short8 bA1 = *(const short8*)&sACT[p1 * AS + ks * 32 + q * 8];
                acc2_00 = __builtin_amdgcn_mfma_f32_16x16x32_bf16(aH, bA0, acc2_00, 0, 0, 0);
                acc2_01 = __builtin_amdgcn_mfma_f32_16x16x32_bf16(aH, bA1, acc2_01, 0, 0, 0);
                acc2_00 = __builtin_amdgcn_mfma_f32_16x16x32_bf16(aL, bA0, acc2_00, 0, 0, 0);
                acc2_01 = __builtin_amdgcn_mfma_f32_16x16x32_bf16(aL, bA1, acc2_01, 0, 0, 0);
            }
        }
        {
            const int cmt = wv * 2 + 1;
            const short8* a2H = (const short8*)(wsu + P2_U + (((b * 2 + 0) * 8 + cmt) * 6) * 512 + lane * 8);
            const short8* a2L = (const short8*)(wsu + P2_U + (((b * 2 + 1) * 8 + cmt) * 6) * 512 + lane * 8);
#pragma unroll
            for (int ks = 0; ks < 6; ++ks) {
                short8 aH = a2H[ks * 64];
                short8 aL = a2L[ks * 64];
                short8 bA0 = *(const short8*)&sACT[p0 * AS + ks * 32 + q * 8];
                short8 bA1 = *(const short8*)&sACT[p1 * AS + ks * 32 + q * 8];
                acc2_10 = __builtin_amdgcn_mfma_f32_16x16x32_bf16(aH, bA0, acc2_10, 0, 0, 0);
                acc2_11 = __builtin_amdgcn_mfma_f32_16x16x32_bf16(aH, bA1, acc2_11, 0, 0, 0);
                acc2_10 = __builtin_amdgcn_mfma_f32_16x16x32_bf16(aL, bA0, acc2_10, 0, 0, 0);
                acc2_11 = __builtin_amdgcn_mfma_f32_16x16x32_bf16(aL, bA1, acc2_11, 0, 0, 0);
            }
        }

        // ---- update: all-constant indices, scalar temporaries only
        const bool last = (it == niter - 1);
#define UPDATE_CELL(CB, P, ACC, XNA, XNB)                                        \
        {                                                                        \
            unsigned long long oh = *(const unsigned long long*)&sXH[(P) * XS + (CB)]; \
            unsigned long long ol = *(const unsigned long long*)&sXL[(P) * XS + (CB)]; \
            float xo0 = bf2f((unsigned short)(oh)) + bf2f((unsigned short)(ol)); \
            float xo1 = bf2f((unsigned short)(oh >> 16)) + bf2f((unsigned short)(ol >> 16)); \
            float xo2 = bf2f((unsigned short)(oh >> 32)) + bf2f((unsigned short)(ol >> 32)); \
            float xo3 = bf2f((unsigned short)(oh >> 48)) + bf2f((unsigned short)(ol >> 48)); \
            float nx0 = xo0 - ((xo0 - (XNA).x) + (ACC)[0]) * invden;             \
            float nx1 = xo1 - ((xo1 - (XNA).y) + (ACC)[1]) * invden;             \
            float nx2 = xo2 - ((xo2 - (XNB).x) + (ACC)[2]) * invden;             \
            float nx3 = xo3 - ((xo3 - (XNB).y) + (ACC)[3]) * invden;             \
            if (last) {                                                          \
                oimg[((CB) + 0) * HW + (P)] = nx0;                               \
                oimg[((CB) + 1) * HW + (P)] = nx1;                               \
                oimg[((CB) + 2) * HW + (P)] = nx2;                               \
                oimg[((CB) + 3) * HW + (P)] = nx3;                               \
            } else {                                                             \
                unsigned short h0 = (unsigned short)(__float_as_uint(nx0) >> 16); \
                unsigned short h1 = (unsigned short)(__float_as_uint(nx1) >> 16); \
                unsigned short h2 = (unsigned short)(__float_as_uint(nx2) >> 16); \
                unsigned short h3 = (unsigned short)(__float_as_uint(nx3) >> 16); \
                unsigned short l0 = (unsigned short)(__float_as_uint(nx0 - bf2f(h0)) >> 16); \
                unsigned short l1 = (unsigned short)(__float_as_uint(nx1 - bf2f(h1)) >> 16); \
                unsigned short l2 = (unsigned short)(__float_as_uint(nx2 - bf2f(h2)) >> 16); \
                unsigned short l3 = (unsigned short)(__float_as_uint(nx3 - bf2f(h3)) >> 16); \
                unsigned long long nh = (unsigned long long)h0 | ((unsigned long long)h1 << 16) \
                                      | ((unsigned long long)h2 << 32) | ((unsigned long long)h3 << 48); \
                unsigned long long nl = (unsigned long long)l0 | ((unsigned long long)l1 << 16) \
                                      | ((unsigned long long)l2 << 32) | ((unsigned long long)l3 << 48); \
                *(unsigned long long*)&sXH[(P) * XS + (CB)] = nh;                \
                *(unsigned long long*)&sXL[(P) * XS + (CB)] = nl;                \
            }                                                                    \
        }
        UPDATE_CELL(cb0, p0, acc2_00, xn00a, xn00b)
        UPDATE_CELL(cb0, p1, acc2_01, xn01a, xn01b)
        UPDATE_CELL(cb1, p0, acc2_10, xn10a, xn10b)
        UPDATE_CELL(cb1, p1, acc2_11, xn11a, xn11b)
#undef UPDATE_CELL
    }
}

extern "C" void kernel_launch(void* const* d_in, const int* in_sizes, int n_in,
                              void* d_out, int out_size, void* d_ws, size_t ws_size,
                              hipStream_t stream) {
    const float* x_noisy = (const float*)d_in[0];
    const float* sigma   = (const float*)d_in[1];
    const float* Qp      = (const float*)d_in[2];
    const float* taus_p  = (const float*)d_in[3];
    const float* lamb    = (const float*)d_in[4];
    const float* eps_om  = (const float*)d_in[5];
    const float* mw1     = (const float*)d_in[6];
    const float* mb1     = (const float*)d_in[7];
    const float* mw2     = (const float*)d_in[8];
    const float* mb2     = (const float*)d_in[9];
    const float* mw3     = (const float*)d_in[10];
    const float* mb3     = (const float*)d_in[11];
    const float* Wf      = (const float*)d_in[12];
    const int*   n_iter  = (const int*)d_in[13];
    float* out = (float*)d_out;
    float* ws  = (float*)d_ws;

    hipLaunchKernelGGL(setup_all, dim3(64), dim3(TPB), 0, stream,
                       sigma, Qp, taus_p, lamb, eps_om,
                       mw1, mb1, mw2, mb2, mw3, mb3, Wf, ws);
    hipLaunchKernelGGL(mfoe_main, dim3(1024), dim3(TPB), 0, stream,
                       x_noisy, ws, out, n_iter);
}

// Round 8
// 452.359 us; speedup vs baseline: 1.1110x; 1.1110x over previous
//
#include <hip/hip_runtime.h>
#include <math.h>

#define F_ 48
#define C_ 128
#define HW 16384
#define SCALE_C 0.999f
#define TPB 256

typedef __attribute__((ext_vector_type(8))) short short8;
typedef __attribute__((ext_vector_type(4))) float floatx4;
typedef __attribute__((ext_vector_type(2))) unsigned int uint2v;

// ---- ws layout ----
// ushort region:
//   P1 frags: [b(2)][hl(2)][mt(12)][ks(4)][lane(64)][j(8)]  = 98304 ushorts
//   P2 frags: [b(2)][hl(2)][cmt(8)][ks(6)][lane(64)][j(8)]  = 98304 ushorts
// float region at float offset 98304:
#define P1_U 0
#define P2_U 98304
#define QEQN_F 98304              // [48][32]: [l*4+g]=qe', [16+g*4+l]=qn'
#define MISC_F (QEQN_F + 1536)    // eps_e, invden
#define XS 152                    // x rows (ushorts): dword stride 76 == 12 mod 32
#define AS 200                    // act rows (ushorts): 192 + pad, dword 100 == 4 mod 32
#define QS 36                     // sQ float stride

__device__ __forceinline__ unsigned short f2bf(float f) {     // RTNE
    unsigned u = __float_as_uint(f);
    unsigned r = u + 0x7fffu + ((u >> 16) & 1u);
    return (unsigned short)(r >> 16);
}
__device__ __forceinline__ float bf2f(unsigned short h) {
    return __uint_as_float(((unsigned)h) << 16);
}

// ---------------- merged setup (R6's, with R4 param layout) ----------------
__global__ void setup_all(const float* __restrict__ sigma,
                          const float* __restrict__ Qp,
                          const float* __restrict__ taus_p,
                          const float* __restrict__ lamb,
                          const float* __restrict__ eps_om,
                          const float* __restrict__ mw1, const float* __restrict__ mb1,
                          const float* __restrict__ mw2, const float* __restrict__ mb2,
                          const float* __restrict__ mw3, const float* __restrict__ mb3,
                          const float* __restrict__ Wf,
                          float* __restrict__ wsf)
{
    __shared__ float sInv[2][F_];
    __shared__ float sLam[2][F_];
    const int tid = threadIdx.x;
    unsigned short* wsu = (unsigned short*)wsf;

    if (tid >= 48 && tid < 50) {
        const int b = tid - 48;
        float lamb_e = expf(lamb[0]);
        float sg = sigma[b];
        float t = sg * 20.0f - 2.0f;
        float h1[F_], h2[F_];
        for (int j = 0; j < F_; ++j) h1[j] = fmaxf(t * mw1[j] + mb1[j], 0.0f);
        for (int j = 0; j < F_; ++j) {
            float s = mb2[j];
            for (int k = 0; k < F_; ++k) s += h1[k] * mw2[k * F_ + j];
            h2[j] = fmaxf(s, 0.0f);
        }
        for (int j = 0; j < F_; ++j) {
            float s = mb3[j];
            for (int k = 0; k < F_; ++k) s += h2[k] * mw3[k * F_ + j];
            float sc = fmaxf(s * 0.05f + sg, 0.0f) + 1e-9f;
            sInv[b][j] = 1.0f / sc;
            sLam[b][j] = lamb_e * sc;
        }
    }
    if (blockIdx.x == 0) {
        if (tid < F_) {
            const int f = tid;
            float Qm[4][4];
            for (int g = 0; g < 4; ++g) {
                float s = 0.f;
                for (int l = 0; l < 4; ++l) s += fabsf(Qp[f * 16 + g * 4 + l]);
                float d = fmaxf(s, 1.0f);
                for (int l = 0; l < 4; ++l) Qm[g][l] = Qp[f * 16 + g * 4 + l] / d;
            }
            double A[4][4];
            for (int i = 0; i < 4; ++i)
                for (int j = 0; j < 4; ++j) {
                    double s = 0.0;
                    for (int g = 0; g < 4; ++g) s += (double)Qm[g][i] * (double)Qm[g][j];
                    A[i][j] = s;
                }
            double M[4][4];
            for (int i = 0; i < 4; ++i) for (int j = 0; j < 4; ++j) M[i][j] = A[i][j];
            for (int it = 0; it < 30; ++it) {
                double T[4][4]; double mx = 0.0;
                for (int i = 0; i < 4; ++i)
                    for (int j = 0; j < 4; ++j) {
                        double s = 0.0;
                        for (int k = 0; k < 4; ++k) s += M[i][k] * M[k][j];
                        T[i][j] = s;
                        double a = fabs(s); if (a > mx) mx = a;
                    }
                if (mx < 1e-300) break;
                double inv = 1.0 / mx;
                for (int i = 0; i < 4; ++i) for (int j = 0; j < 4; ++j) M[i][j] = T[i][j] * inv;
            }
            int jb = 0; double bn = -1.0;
            for (int j = 0; j < 4; ++j) {
                double nn = 0.0;
                for (int i = 0; i < 4; ++i) nn += M[i][j] * M[i][j];
                if (nn > bn) { bn = nn; jb = j; }
            }
            double v[4]; for (int i = 0; i < 4; ++i) v[i] = M[i][jb];
            double Av[4];
            for (int i = 0; i < 4; ++i) {
                double s = 0.0;
                for (int j = 0; j < 4; ++j) s += A[i][j] * v[j];
                Av[i] = s;
            }
            double vv = 0.0, vav = 0.0;
            for (int i = 0; i < 4; ++i) { vv += v[i] * v[i]; vav += v[i] * Av[i]; }
            float lamf = (float)((vv > 0.0) ? (vav / vv) : 0.0);
            float tau = expf(fmaxf(taus_p[f], 0.0f));
            float qsv = SCALE_C / tau;
            // R4 layout: [l*4+g] = qe'(l,g), [16+g*4+l] = qn'(g,l)
            for (int l = 0; l < 4; ++l)
                for (int g = 0; g < 4; ++g)
                    wsf[QEQN_F + f * 32 + l * 4 + g] = qsv * Qm[l][g] / lamf;
            for (int g = 0; g < 4; ++g)
                for (int l = 0; l < 4; ++l)
                    wsf[QEQN_F + f * 32 + 16 + g * 4 + l] = SCALE_C * Qm[g][l];
        }
        if (tid == 50) {
            float lamb_e = expf(lamb[0]);
            float eps_e = expf(eps_om[0]);
            wsf[MISC_F + 0] = eps_e;
            wsf[MISC_F + 1] = 1.0f / (1.0f + lamb_e * (1.0f + eps_e));
        }
    }
    __syncthreads();

    for (int i = blockIdx.x * TPB + tid; i < 49152; i += gridDim.x * TPB) {
        if (i < 24576) {
            int j = i & 7, lane = (i >> 3) & 63;
            int t = i >> 9;
            int ks = t & 3, mt = t >> 2;
            int m = lane & 15, q = lane >> 4;
            int r = mt * 16 + m;
            int c = ks * 32 + q * 8 + j;
            int f = r >> 2, g = r & 3;
            float w = Wf[(g * F_ + f) * C_ + c];
#pragma unroll
            for (int b = 0; b < 2; ++b) {
                float v = w * sInv[b][f];
                unsigned short h = (unsigned short)(__float_as_uint(v) >> 16);
                float lo = v - bf2f(h);
                unsigned short l = (unsigned short)(__float_as_uint(lo) >> 16);
                wsu[P1_U + ((((b * 2 + 0) * 12 + mt) * 4 + ks) * 64 + lane) * 8 + j] = h;
                wsu[P1_U + ((((b * 2 + 1) * 12 + mt) * 4 + ks) * 64 + lane) * 8 + j] = l;
            }
        } else {
            int ii = i - 24576;
            int j = ii & 7, lane = (ii >> 3) & 63;
            int t = ii >> 9;
            int ks = t % 6, cmt = t / 6;
            int m = lane & 15, q = lane >> 4;
            int cch = cmt * 16 + m;
            int r = ks * 32 + q * 8 + j;
            int f = r >> 2, g = r & 3;
            float w = Wf[(g * F_ + f) * C_ + cch];
#pragma unroll
            for (int b = 0; b < 2; ++b) {
                float v = w * sLam[b][f];
                unsigned short h = (unsigned short)(__float_as_uint(v) >> 16);
                float lo = v - bf2f(h);
                unsigned short l = (unsigned short)(__float_as_uint(lo) >> 16);
                wsu[P2_U + ((((b * 2 + 0) * 8 + cmt) * 6 + ks) * 64 + lane) * 8 + j] = h;
                wsu[P2_U + ((((b * 2 + 1) * 8 + cmt) * 6 + ks) * 64 + lane) * 8 + j] = l;
            }
        }
    }
}

// R4's proj4 (array version — measured clean at 182 µs)
__device__ __forceinline__ void proj4(const float v[4], float o[4]) {
    float a0 = fabsf(v[0]), a1 = fabsf(v[1]), a2 = fabsf(v[2]), a3 = fabsf(v[3]);
    float sum = a0 + a1 + a2 + a3;
    float t0 = fmaxf(a0, a1), u0 = fminf(a0, a1);
    float t1 = fmaxf(a2, a3), u1 = fminf(a2, a3);
    float s0 = fmaxf(t0, t1), m0 = fminf(t0, t1);
    float m1 = fmaxf(u0, u1), s3 = fminf(u0, u1);
    float s1 = fmaxf(m1, m0), s2 = fminf(m1, m0);
    float c2 = s0 + s1, c3 = c2 + s2, c4 = c3 + s3;
    float th = s0 - 1.0f, rh = 1.0f;
    if (s1 * 2.0f > c2 - 1.0f) { th = c2 - 1.0f; rh = 2.0f; }
    if (s2 * 3.0f > c3 - 1.0f) { th = c3 - 1.0f; rh = 3.0f; }
    if (s3 * 4.0f > c4 - 1.0f) { th = c4 - 1.0f; rh = 4.0f; }
    float theta = fmaxf(th / rh, 0.0f);
    bool inside = (sum <= 1.0f);
#pragma unroll
    for (int g = 0; g < 4; ++g) {
        float ag = fabsf(v[g]);
        float pg = copysignf(fmaxf(ag - theta, 0.0f), v[g]);
        o[g] = inside ? v[g] : pg;
    }
}

// ---------------- main: R4 structure, full-K act (2 barriers/iter) ----------------
__global__ __launch_bounds__(TPB, 4) void mfoe_main(
    const float* __restrict__ xnoisy,
    const float* __restrict__ wsf,
    float* __restrict__ out,
    const int* __restrict__ n_iter_p)
{
    __shared__ __align__(16) unsigned short sXH[32 * XS];
    __shared__ __align__(16) unsigned short sXL[32 * XS];
    __shared__ __align__(16) unsigned short sACT[32 * AS];
    __shared__ __align__(16) float sQ[F_ * QS];

    const int tid = threadIdx.x;
    const int lane = tid & 63;
    const int wv = __builtin_amdgcn_readfirstlane(tid >> 6);
    const int n = lane & 15;
    const int q = lane >> 4;
    const int blk = blockIdx.x;
    const int b = blk >> 9;
    const int pix0 = (blk & 511) << 5;

    const float* __restrict__ xin = xnoisy + b * (C_ * HW) + pix0;
    float* __restrict__ oimg = out + b * (C_ * HW) + pix0;
    const unsigned short* __restrict__ wsu = (const unsigned short*)wsf;
    const int niter = *n_iter_p;

    if (niter == 0) {
        for (int i = tid; i < C_ * 32; i += TPB) {
            int p = i & 31, c = i >> 5;
            oimg[c * HW + p] = xin[c * HW + p];
        }
        return;
    }

    // stage x -> LDS bf16 hi/lo (truncation split)
    for (int i = tid; i < C_ * 32; i += TPB) {
        int p = i & 31, c = i >> 5;
        float v = xin[c * HW + p];
        unsigned short h = (unsigned short)(__float_as_uint(v) >> 16);
        float lo = v - bf2f(h);
        sXH[p * XS + c] = h;
        sXL[p * XS + c] = (unsigned short)(__float_as_uint(lo) >> 16);
    }
    // stage activation params
    for (int i = tid; i < F_ * 32; i += TPB)
        sQ[(i >> 5) * QS + (i & 31)] = wsf[QEQN_F + i];

    // preload this thread's x_noisy values (update layout, R4 mapping)
    float xnr[16];
#pragma unroll
    for (int j = 0; j < 4; ++j) {
        int jw = wv * 4 + j, cmt = jw >> 1, nt = jw & 1;
        int p = nt * 16 + n;
#pragma unroll
        for (int reg = 0; reg < 4; ++reg)
            xnr[j * 4 + reg] = xin[(cmt * 16 + q * 4 + reg) * HW + p];
    }
    const float eps_e = wsf[MISC_F + 0];
    const float invden = wsf[MISC_F + 1];

    for (int it = 0; it < niter; ++it) {
        __syncthreads();   // x ready (and sQ on iter 0)
        // ---- pass 1: 24 (mt,nt) jobs, 6 per wave, one acc at a time (R4 profile)
#pragma unroll 1
        for (int j = 0; j < 6; ++j) {
            int jw = wv * 6 + j, mt = jw >> 1, nt = jw & 1;
            int p = nt * 16 + n;
            floatx4 acc = (floatx4){0.f, 0.f, 0.f, 0.f};
            const short8* aHp = (const short8*)(wsu + P1_U + (((b * 2 + 0) * 12 + mt) * 4) * 512 + lane * 8);
            const short8* aLp = (const short8*)(wsu + P1_U + (((b * 2 + 1) * 12 + mt) * 4) * 512 + lane * 8);
#pragma unroll
            for (int ks = 0; ks < 4; ++ks) {
                short8 aH = aHp[ks * 64];
                short8 aL = aLp[ks * 64];
                short8 bH = *(const short8*)&sXH[p * XS + ks * 32 + q * 8];
                short8 bL = *(const short8*)&sXL[p * XS + ks * 32 + q * 8];
                acc = __builtin_amdgcn_mfma_f32_16x16x32_bf16(aH, bH, acc, 0, 0, 0);
                acc = __builtin_amdgcn_mfma_f32_16x16x32_bf16(aH, bL, acc, 0, 0, 0);
                acc = __builtin_amdgcn_mfma_f32_16x16x32_bf16(aL, bH, acc, 0, 0, 0);
            }
            // ---- activation in D-regs (R4 verbatim): lane owns (f, pixel p)
            int f = mt * 4 + q;
            float qv[32];
#pragma unroll
            for (int k = 0; k < 8; ++k)
                *(floatx4*)&qv[4 * k] = *(const floatx4*)&sQ[f * QS + 4 * k];
            float v[4] = {acc[0], acc[1], acc[2], acc[3]};
            float pv[4]; proj4(v, pv);
            float y[4];
#pragma unroll
            for (int l = 0; l < 4; ++l)
                y[l] = fmaf(qv[l * 4 + 0], v[0], fmaf(qv[l * 4 + 1], v[1],
                       fmaf(qv[l * 4 + 2], v[2], qv[l * 4 + 3] * v[3])));
            float py[4]; proj4(y, py);
            float m2[4];
#pragma unroll
            for (int g = 0; g < 4; ++g) m2[g] = fmaf(eps_e, y[g], py[g]);
            unsigned pk0, pk1;
            {
                float a0, a1;
                float gcc0 = fmaf(qv[16 + 0], m2[0], fmaf(qv[16 + 4], m2[1],
                             fmaf(qv[16 + 8], m2[2], qv[16 + 12] * m2[3])));
                a0 = fmaf(eps_e, v[0], pv[0]) - gcc0;
                float gcc1 = fmaf(qv[17 + 0], m2[0], fmaf(qv[17 + 4], m2[1],
                             fmaf(qv[17 + 8], m2[2], qv[17 + 12] * m2[3])));
                a1 = fmaf(eps_e, v[1], pv[1]) - gcc1;
                pk0 = ((unsigned)f2bf(a1) << 16) | f2bf(a0);
                float gcc2 = fmaf(qv[18 + 0], m2[0], fmaf(qv[18 + 4], m2[1],
                             fmaf(qv[18 + 8], m2[2], qv[18 + 12] * m2[3])));
                a0 = fmaf(eps_e, v[2], pv[2]) - gcc2;
                float gcc3 = fmaf(qv[19 + 0], m2[0], fmaf(qv[19 + 4], m2[1],
                             fmaf(qv[19 + 8], m2[2], qv[19 + 12] * m2[3])));
                a1 = fmaf(eps_e, v[3], pv[3]) - gcc3;
                pk1 = ((unsigned)f2bf(a1) << 16) | f2bf(a0);
            }
            *(uint2v*)&sACT[p * AS + mt * 16 + q * 4] = (uint2v){pk0, pk1};
        }
        __syncthreads();   // act ready; all pass-1 x reads done
        // ---- pass 2: 16 (cmt,nt) jobs, 4 per wave, full K=192 (R4 profile)
        floatx4 acc2[4];
#pragma unroll
        for (int j = 0; j < 4; ++j) acc2[j] = (floatx4){0.f, 0.f, 0.f, 0.f};
#pragma unroll
        for (int j = 0; j < 4; ++j) {
            int jw = wv * 4 + j, cmt = jw >> 1, nt = jw & 1;
            int p = nt * 16 + n;
            const short8* a2H = (const short8*)(wsu + P2_U + (((b * 2 + 0) * 8 + cmt) * 6) * 512 + lane * 8);
            const short8* a2L = (const short8*)(wsu + P2_U + (((b * 2 + 1) * 8 + cmt) * 6) * 512 + lane * 8);
            floatx4 a = acc2[j];
#pragma unroll
            for (int ks = 0; ks < 6; ++ks) {
                short8 aH = a2H[ks * 64];
                short8 aL = a2L[ks * 64];
                short8 bA = *(const short8*)&sACT[p * AS + ks * 32 + q * 8];
                a = __builtin_amdgcn_mfma_f32_16x16x32_bf16(aH, bA, a, 0, 0, 0);
                a = __builtin_amdgcn_mfma_f32_16x16x32_bf16(aL, bA, a, 0, 0, 0);
            }
            acc2[j] = a;
        }
        // ---- update: R4 verbatim (owner LDS round-trip, trunc hi/lo repack)
        const bool last = (it == niter - 1);
#pragma unroll
        for (int j = 0; j < 4; ++j) {
            int jw = wv * 4 + j, cmt = jw >> 1, nt = jw & 1;
            int p = nt * 16 + n;
            int cb = cmt * 16 + q * 4;
            unsigned long long oh = *(const unsigned long long*)&sXH[p * XS + cb];
            unsigned long long ol = *(const unsigned long long*)&sXL[p * XS + cb];
            unsigned long long nh = 0ull, nl = 0ull;
#pragma unroll
            for (int reg = 0; reg < 4; ++reg) {
                float xo = bf2f((unsigned short)(oh >> (16 * reg))) +
                           bf2f((unsigned short)(ol >> (16 * reg)));
                float nx = xo - (xo - xnr[j * 4 + reg] + acc2[j][reg]) * invden;
                if (last) oimg[(cb + reg) * HW + p] = nx;
                unsigned short hh = (unsigned short)(__float_as_uint(nx) >> 16);
                float lo = nx - bf2f(hh);
                unsigned short ll = (unsigned short)(__float_as_uint(lo) >> 16);
                nh |= ((unsigned long long)hh) << (16 * reg);
                nl |= ((unsigned long long)ll) << (16 * reg);
            }
            *(unsigned long long*)&sXH[p * XS + cb] = nh;
            *(unsigned long long*)&sXL[p * XS + cb] = nl;
        }
    }
}

extern "C" void kernel_launch(void* const* d_in, const int* in_sizes, int n_in,
                              void* d_out, int out_size, void* d_ws, size_t ws_size,
                              hipStream_t stream) {
    const float* x_noisy = (const float*)d_in[0];
    const float* sigma   = (const float*)d_in[1];
    const float* Qp      = (const float*)d_in[2];
    const float* taus_p  = (const float*)d_in[3];
    const float* lamb    = (const float*)d_in[4];
    const float* eps_om  = (const float*)d_in[5];
    const float* mw1     = (const float*)d_in[6];
    const float* mb1     = (const float*)d_in[7];
    const float* mw2     = (const float*)d_in[8];
    const float* mb2     = (const float*)d_in[9];
    const float* mw3     = (const float*)d_in[10];
    const float* mb3     = (const float*)d_in[11];
    const float* Wf      = (const float*)d_in[12];
    const int*   n_iter  = (const int*)d_in[13];
    float* out = (float*)d_out;
    float* ws  = (float*)d_ws;

    hipLaunchKernelGGL(setup_all, dim3(64), dim3(TPB), 0, stream,
                       sigma, Qp, taus_p, lamb, eps_om,
                       mw1, mb1, mw2, mb2, mw3, mb3, Wf, ws);
    hipLaunchKernelGGL(mfoe_main, dim3(1024), dim3(TPB), 0, stream,
                       x_noisy, ws, out, n_iter);
}

// Round 9
// 332.982 us; speedup vs baseline: 1.5093x; 1.3585x over previous
//
#include <hip/hip_runtime.h>
#include <math.h>

#define F_ 48
#define C_ 128
#define HW 16384
#define SCALE_C 0.999f
#define TPB 256

typedef __attribute__((ext_vector_type(8))) short short8;
typedef __attribute__((ext_vector_type(4))) float floatx4;

// ---- ws layout ----
// ushort region (fragments):
//   P1 frags: [b(2)][hl(2)][mt(12)][ks(4)][lane(64)][j(8)]  = 98304 ushorts
//   P2 frags: [b(2)][hl(2)][cmt(8)][ks(6)][lane(64)][j(8)]  = 98304 ushorts
// float region at float offset 98304 (byte 393216):
#define P1_U 0
#define P2_U 98304
#define QEQN_F 98304              // [48][32]
#define MISC_F (QEQN_F + 1536)    // eps_e, invden
#define SINV_F (MISC_F + 2)       // [2][48] 1/scaling
#define SLAM_F (SINV_F + 96)      // [2][48] lamb_e*scaling

// LDS strides (bf16 units); XS: 76 dwords/row == 12 mod 32; AS: 52 == 20 mod 32.
#define XS 152
#define AS 104
#define QS 36    // sQ row stride in floats (16B-aligned, 2-way bank alias = free)

__device__ __forceinline__ unsigned short f2bf(float f) {     // RTNE
    unsigned u = __float_as_uint(f);
    unsigned r = u + 0x7fffu + ((u >> 16) & 1u);
    return (unsigned short)(r >> 16);
}
__device__ __forceinline__ float bf2f(unsigned short h) {
    return __uint_as_float(((unsigned)h) << 16);
}

// ---------------- setup: math (1 block, tiny) ----------------
__global__ void setup_math(const float* __restrict__ sigma,
                           const float* __restrict__ Qp,
                           const float* __restrict__ taus_p,
                           const float* __restrict__ lamb,
                           const float* __restrict__ eps_om,
                           const float* __restrict__ mw1, const float* __restrict__ mb1,
                           const float* __restrict__ mw2, const float* __restrict__ mb2,
                           const float* __restrict__ mw3, const float* __restrict__ mb3,
                           float* __restrict__ wsf)
{
    const int tid = threadIdx.x;
    if (tid < F_) {
        const int f = tid;
        float Qm[4][4];
        for (int g = 0; g < 4; ++g) {
            float s = 0.f;
            for (int l = 0; l < 4; ++l) s += fabsf(Qp[f * 16 + g * 4 + l]);
            float d = fmaxf(s, 1.0f);
            for (int l = 0; l < 4; ++l) Qm[g][l] = Qp[f * 16 + g * 4 + l] / d;
        }
        double A[4][4];
        for (int i = 0; i < 4; ++i)
            for (int j = 0; j < 4; ++j) {
                double s = 0.0;
                for (int g = 0; g < 4; ++g) s += (double)Qm[g][i] * (double)Qm[g][j];
                A[i][j] = s;
            }
        double M[4][4];
        for (int i = 0; i < 4; ++i) for (int j = 0; j < 4; ++j) M[i][j] = A[i][j];
        for (int it = 0; it < 30; ++it) {
            double T[4][4]; double mx = 0.0;
            for (int i = 0; i < 4; ++i)
                for (int j = 0; j < 4; ++j) {
                    double s = 0.0;
                    for (int k = 0; k < 4; ++k) s += M[i][k] * M[k][j];
                    T[i][j] = s;
                    double a = fabs(s); if (a > mx) mx = a;
                }
            if (mx < 1e-300) break;
            double inv = 1.0 / mx;
            for (int i = 0; i < 4; ++i) for (int j = 0; j < 4; ++j) M[i][j] = T[i][j] * inv;
        }
        int jb = 0; double bn = -1.0;
        for (int j = 0; j < 4; ++j) {
            double nn = 0.0;
            for (int i = 0; i < 4; ++i) nn += M[i][j] * M[i][j];
            if (nn > bn) { bn = nn; jb = j; }
        }
        double v[4]; for (int i = 0; i < 4; ++i) v[i] = M[i][jb];
        double Av[4];
        for (int i = 0; i < 4; ++i) {
            double s = 0.0;
            for (int j = 0; j < 4; ++j) s += A[i][j] * v[j];
            Av[i] = s;
        }
        double vv = 0.0, vav = 0.0;
        for (int i = 0; i < 4; ++i) { vv += v[i] * v[i]; vav += v[i] * Av[i]; }
        float lamf = (float)((vv > 0.0) ? (vav / vv) : 0.0);
        float tau = expf(fmaxf(taus_p[f], 0.0f));
        float qsv = SCALE_C / tau;
        for (int l = 0; l < 4; ++l)
            for (int g = 0; g < 4; ++g)
                wsf[QEQN_F + f * 32 + l * 4 + g] = qsv * Qm[l][g] / lamf;
        for (int g = 0; g < 4; ++g)
            for (int l = 0; l < 4; ++l)
                wsf[QEQN_F + f * 32 + 16 + g * 4 + l] = SCALE_C * Qm[g][l];
    }
    if (tid >= 48 && tid < 50) {
        const int b = tid - 48;
        float lamb_e = expf(lamb[0]);
        float sg = sigma[b];
        float t = sg * 20.0f - 2.0f;
        float h1[F_], h2[F_];
        for (int j = 0; j < F_; ++j) h1[j] = fmaxf(t * mw1[j] + mb1[j], 0.0f);
        for (int j = 0; j < F_; ++j) {
            float s = mb2[j];
            for (int k = 0; k < F_; ++k) s += h1[k] * mw2[k * F_ + j];
            h2[j] = fmaxf(s, 0.0f);
        }
        for (int j = 0; j < F_; ++j) {
            float s = mb3[j];
            for (int k = 0; k < F_; ++k) s += h2[k] * mw3[k * F_ + j];
            float sc = fmaxf(s * 0.05f + sg, 0.0f) + 1e-9f;
            wsf[SINV_F + b * F_ + j] = 1.0f / sc;
            wsf[SLAM_F + b * F_ + j] = lamb_e * sc;
        }
    }
    if (tid == 50) {
        float lamb_e = expf(lamb[0]);
        float eps_e = expf(eps_om[0]);
        wsf[MISC_F + 0] = eps_e;
        wsf[MISC_F + 1] = 1.0f / (1.0f + lamb_e * (1.0f + eps_e));
    }
}

// ---------------- setup: fragment packing (grid-parallel) ----------------
__global__ void setup_pack(const float* __restrict__ Wf, float* __restrict__ wsf)
{
    unsigned short* wsu = (unsigned short*)wsf;
    const int gtid = blockIdx.x * TPB + threadIdx.x;
    for (int i = gtid; i < 49152; i += gridDim.x * TPB) {
        if (i < 24576) {
            // pass-1 A frags: M = row r (f*4+g), K = channel c; fold 1/scaling
            int j = i & 7, lane = (i >> 3) & 63;
            int t = i >> 9;                // 0..47
            int ks = t & 3, mt = t >> 2;
            int m = lane & 15, q = lane >> 4;
            int r = mt * 16 + m;
            int c = ks * 32 + q * 8 + j;
            int f = r >> 2, g = r & 3;
            float w = Wf[(g * F_ + f) * C_ + c];
#pragma unroll
            for (int b = 0; b < 2; ++b) {
                float v = w * wsf[SINV_F + b * F_ + f];
                unsigned short h = (unsigned short)(__float_as_uint(v) >> 16);
                float lo = v - bf2f(h);
                unsigned short l = (unsigned short)(__float_as_uint(lo) >> 16);
                wsu[P1_U + ((((b * 2 + 0) * 12 + mt) * 4 + ks) * 64 + lane) * 8 + j] = h;
                wsu[P1_U + ((((b * 2 + 1) * 12 + mt) * 4 + ks) * 64 + lane) * 8 + j] = l;
            }
        } else {
            // pass-2 A frags: M = channel, K = row; fold lamb_e*scaling
            int ii = i - 24576;
            int j = ii & 7, lane = (ii >> 3) & 63;
            int t = ii >> 9;
            int ks = t % 6, cmt = t / 6;
            int m = lane & 15, q = lane >> 4;
            int cch = cmt * 16 + m;
            int r = ks * 32 + q * 8 + j;
            int f = r >> 2, g = r & 3;
            float w = Wf[(g * F_ + f) * C_ + cch];
#pragma unroll
            for (int b = 0; b < 2; ++b) {
                float v = w * wsf[SLAM_F + b * F_ + f];
                unsigned short h = (unsigned short)(__float_as_uint(v) >> 16);
                float lo = v - bf2f(h);
                unsigned short l = (unsigned short)(__float_as_uint(lo) >> 16);
                wsu[P2_U + ((((b * 2 + 0) * 8 + cmt) * 6 + ks) * 64 + lane) * 8 + j] = h;
                wsu[P2_U + ((((b * 2 + 1) * 8 + cmt) * 6 + ks) * 64 + lane) * 8 + j] = l;
            }
        }
    }
}

// Euclidean projection of a 4-vector onto the unit l1 ball (per lane, in regs)
__device__ __forceinline__ void proj4(const float v[4], float o[4]) {
    float a0 = fabsf(v[0]), a1 = fabsf(v[1]), a2 = fabsf(v[2]), a3 = fabsf(v[3]);
    float sum = a0 + a1 + a2 + a3;
    float t0 = fmaxf(a0, a1), u0 = fminf(a0, a1);
    float t1 = fmaxf(a2, a3), u1 = fminf(a2, a3);
    float s0 = fmaxf(t0, t1), m0 = fminf(t0, t1);
    float m1 = fmaxf(u0, u1), s3 = fminf(u0, u1);
    float s1 = fmaxf(m1, m0), s2 = fminf(m1, m0);
    float c2 = s0 + s1, c3 = c2 + s2, c4 = c3 + s3;
    float th = s0 - 1.0f, rh = 1.0f;
    if (s1 * 2.0f > c2 - 1.0f) { th = c2 - 1.0f; rh = 2.0f; }
    if (s2 * 3.0f > c3 - 1.0f) { th = c3 - 1.0f; rh = 3.0f; }
    if (s3 * 4.0f > c4 - 1.0f) { th = c4 - 1.0f; rh = 4.0f; }
    float theta = fmaxf(th / rh, 0.0f);
    bool inside = (sum <= 1.0f);
#pragma unroll
    for (int g = 0; g < 4; ++g) {
        float ag = fabsf(v[g]);
        float pg = copysignf(fmaxf(ag - theta, 0.0f), v[g]);
        o[g] = inside ? v[g] : pg;
    }
}

// ---------------- main: 32-pixel tile per block, 1024 blocks ----------------
__global__ __launch_bounds__(TPB, 4) void mfoe_main(
    const float* __restrict__ xnoisy,
    const float* __restrict__ wsf,
    float* __restrict__ out,
    const int* __restrict__ n_iter_p)
{
    __shared__ __align__(16) unsigned short sXH[32 * XS];
    __shared__ __align__(16) unsigned short sXL[32 * XS];
    __shared__ __align__(16) unsigned short sACT[32 * AS];
    __shared__ __align__(16) float sQ[F_ * QS];

    const int tid = threadIdx.x;
    const int lane = tid & 63;
    const int wv = __builtin_amdgcn_readfirstlane(tid >> 6);   // SGPR wave id
    const int n = lane & 15;
    const int q = lane >> 4;
    const int blk = blockIdx.x;
    const int b = blk >> 9;                 // 512 blocks per image
    const int pix0 = (blk & 511) << 5;      // 32 pixels per block

    const float* __restrict__ xin = xnoisy + b * (C_ * HW) + pix0;
    float* __restrict__ oimg = out + b * (C_ * HW) + pix0;
    const unsigned short* __restrict__ wsu = (const unsigned short*)wsf;
    const int niter = *n_iter_p;

    if (niter == 0) {
        for (int i = tid; i < C_ * 32; i += TPB) {
            int p = i & 31, c = i >> 5;
            oimg[c * HW + p] = xin[c * HW + p];
        }
        return;
    }

    // stage x -> LDS bf16 hi/lo (truncation split: lo absorbs hi's error)
    for (int i = tid; i < C_ * 32; i += TPB) {
        int p = i & 31, c = i >> 5;
        float v = xin[c * HW + p];
        unsigned short h = (unsigned short)(__float_as_uint(v) >> 16);
        float lo = v - bf2f(h);
        sXH[p * XS + c] = h;
        sXL[p * XS + c] = (unsigned short)(__float_as_uint(lo) >> 16);
    }
    // stage activation params -> LDS (padded rows)
    for (int i = tid; i < F_ * 32; i += TPB)
        sQ[(i >> 5) * QS + (i & 31)] = wsf[QEQN_F + i];

    // preload this thread's x_noisy values (update layout)
    float xnr[16];
#pragma unroll
    for (int j = 0; j < 4; ++j) {
        int jw = wv * 4 + j, cmt = jw >> 1, nt = jw & 1;
        int p = nt * 16 + n;
#pragma unroll
        for (int reg = 0; reg < 4; ++reg)
            xnr[j * 4 + reg] = xin[(cmt * 16 + q * 4 + reg) * HW + p];
    }
    const float eps_e = wsf[MISC_F + 0];
    const float invden = wsf[MISC_F + 1];

    for (int it = 0; it < niter; ++it) {
        floatx4 acc2[4];
#pragma unroll
        for (int j = 0; j < 4; ++j) acc2[j] = (floatx4){0.f, 0.f, 0.f, 0.f};

#pragma unroll 1
        for (int h = 0; h < 2; ++h) {
            __syncthreads();   // x ready / act buffer free
            // ---- pass 1: 12 (mtile,ntile) jobs per half, 3 per wave
#pragma unroll 1
            for (int j = 0; j < 3; ++j) {
                int jw = wv * 3 + j, mtl = jw >> 1, nt = jw & 1;
                int mt = h * 6 + mtl;
                int p = nt * 16 + n;
                floatx4 acc = (floatx4){0.f, 0.f, 0.f, 0.f};
                const short8* aHp = (const short8*)(wsu + P1_U + (((b * 2 + 0) * 12 + mt) * 4) * 512 + lane * 8);
                const short8* aLp = (const short8*)(wsu + P1_U + (((b * 2 + 1) * 12 + mt) * 4) * 512 + lane * 8);
#pragma unroll
                for (int ks = 0; ks < 4; ++ks) {
                    short8 aH = aHp[ks * 64];
                    short8 aL = aLp[ks * 64];
                    short8 bH = *(const short8*)&sXH[p * XS + ks * 32 + q * 8];
                    short8 bL = *(const short8*)&sXL[p * XS + ks * 32 + q * 8];
                    acc = __builtin_amdgcn_mfma_f32_16x16x32_bf16(aH, bH, acc, 0, 0, 0);
                    acc = __builtin_amdgcn_mfma_f32_16x16x32_bf16(aH, bL, acc, 0, 0, 0);
                    acc = __builtin_amdgcn_mfma_f32_16x16x32_bf16(aL, bH, acc, 0, 0, 0);
                }
                // ---- activation in D-regs: lane owns (f, pixel p)
                int f = h * 24 + mtl * 4 + q;
                float qv[32];
#pragma unroll
                for (int k = 0; k < 8; ++k)
                    *(floatx4*)&qv[4 * k] = *(const floatx4*)&sQ[f * QS + 4 * k];
                float v[4] = {acc[0], acc[1], acc[2], acc[3]};
                float pv[4]; proj4(v, pv);
                float y[4];
#pragma unroll
                for (int l = 0; l < 4; ++l)
                    y[l] = fmaf(qv[l * 4 + 0], v[0], fmaf(qv[l * 4 + 1], v[1],
                           fmaf(qv[l * 4 + 2], v[2], qv[l * 4 + 3] * v[3])));
                float py[4]; proj4(y, py);
                float m2[4];
#pragma unroll
                for (int g = 0; g < 4; ++g) m2[g] = fmaf(eps_e, y[g], py[g]);
                unsigned pk0, pk1;
                {
                    float a0, a1;
                    float gcc0 = fmaf(qv[16 + 0], m2[0], fmaf(qv[16 + 4], m2[1],
                                 fmaf(qv[16 + 8], m2[2], qv[16 + 12] * m2[3])));
                    a0 = fmaf(eps_e, v[0], pv[0]) - gcc0;
                    float gcc1 = fmaf(qv[17 + 0], m2[0], fmaf(qv[17 + 4], m2[1],
                                 fmaf(qv[17 + 8], m2[2], qv[17 + 12] * m2[3])));
                    a1 = fmaf(eps_e, v[1], pv[1]) - gcc1;
                    pk0 = ((unsigned)f2bf(a1) << 16) | f2bf(a0);
                    float gcc2 = fmaf(qv[18 + 0], m2[0], fmaf(qv[18 + 4], m2[1],
                                 fmaf(qv[18 + 8], m2[2], qv[18 + 12] * m2[3])));
                    a0 = fmaf(eps_e, v[2], pv[2]) - gcc2;
                    float gcc3 = fmaf(qv[19 + 0], m2[0], fmaf(qv[19 + 4], m2[1],
                                 fmaf(qv[19 + 8], m2[2], qv[19 + 12] * m2[3])));
                    a1 = fmaf(eps_e, v[3], pv[3]) - gcc3;
                    pk1 = ((unsigned)f2bf(a1) << 16) | f2bf(a0);
                }
                unsigned long long pk = ((unsigned long long)pk1 << 32) | pk0;
                *(unsigned long long*)&sACT[p * AS + mtl * 16 + q * 4] = pk;
            }
            __syncthreads();   // act ready
            // ---- pass 2 partial: 16 (ctile,ntile) jobs, 4 per wave
#pragma unroll
            for (int j = 0; j < 4; ++j) {
                int jw = wv * 4 + j, cmt = jw >> 1, nt = jw & 1;
                int p = nt * 16 + n;
                const short8* a2H = (const short8*)(wsu + P2_U + (((b * 2 + 0) * 8 + cmt) * 6 + h * 3) * 512 + lane * 8);
                const short8* a2L = (const short8*)(wsu + P2_U + (((b * 2 + 1) * 8 + cmt) * 6 + h * 3) * 512 + lane * 8);
                floatx4 a = acc2[j];
#pragma unroll
                for (int ksl = 0; ksl < 3; ++ksl) {
                    short8 aH = a2H[ksl * 64];
                    short8 aL = a2L[ksl * 64];
                    short8 bA = *(const short8*)&sACT[p * AS + ksl * 32 + q * 8];
                    a = __builtin_amdgcn_mfma_f32_16x16x32_bf16(aH, bA, a, 0, 0, 0);
                    a = __builtin_amdgcn_mfma_f32_16x16x32_bf16(aL, bA, a, 0, 0, 0);
                }
                acc2[j] = a;
            }
        }
        // ---- update: thread owns (cmt,q,nt) cells; trunc hi/lo repack
        const bool last = (it == niter - 1);
#pragma unroll
        for (int j = 0; j < 4; ++j) {
            int jw = wv * 4 + j, cmt = jw >> 1, nt = jw & 1;
            int p = nt * 16 + n;
            int cb = cmt * 16 + q * 4;
            unsigned long long oh = *(const unsigned long long*)&sXH[p * XS + cb];
            unsigned long long ol = *(const unsigned long long*)&sXL[p * XS + cb];
            unsigned long long nh = 0ull, nl = 0ull;
#pragma unroll
            for (int reg = 0; reg < 4; ++reg) {
                float xo = bf2f((unsigned short)(oh >> (16 * reg))) +
                           bf2f((unsigned short)(ol >> (16 * reg)));
                float nx = xo - (xo - xnr[j * 4 + reg] + acc2[j][reg]) * invden;
                if (last) oimg[(cb + reg) * HW + p] = nx;
                unsigned short hh = (unsigned short)(__float_as_uint(nx) >> 16);
                float lo = nx - bf2f(hh);
                unsigned short ll = (unsigned short)(__float_as_uint(lo) >> 16);
                nh |= ((unsigned long long)hh) << (16 * reg);
                nl |= ((unsigned long long)ll) << (16 * reg);
            }
            *(unsigned long long*)&sXH[p * XS + cb] = nh;
            *(unsigned long long*)&sXL[p * XS + cb] = nl;
        }
    }
}

extern "C" void kernel_launch(void* const* d_in, const int* in_sizes, int n_in,
                              void* d_out, int out_size, void* d_ws, size_t ws_size,
                              hipStream_t stream) {
    const float* x_noisy = (const float*)d_in[0];
    const float* sigma   = (const float*)d_in[1];
    const float* Qp      = (const float*)d_in[2];
    const float* taus_p  = (const float*)d_in[3];
    const float* lamb    = (const float*)d_in[4];
    const float* eps_om  = (const float*)d_in[5];
    const float* mw1     = (const float*)d_in[6];
    const float* mb1     = (const float*)d_in[7];
    const float* mw2     = (const float*)d_in[8];
    const float* mb2     = (const float*)d_in[9];
    const float* mw3     = (const float*)d_in[10];
    const float* mb3     = (const float*)d_in[11];
    const float* Wf      = (const float*)d_in[12];
    const int*   n_iter  = (const int*)d_in[13];
    float* out = (float*)d_out;
    float* ws  = (float*)d_ws;

    hipLaunchKernelGGL(setup_math, dim3(1), dim3(64), 0, stream,
                       sigma, Qp, taus_p, lamb, eps_om,
                       mw1, mb1, mw2, mb2, mw3, mb3, ws);
    hipLaunchKernelGGL(setup_pack, dim3(192), dim3(TPB), 0, stream, Wf, ws);
    hipLaunchKernelGGL(mfoe_main, dim3(1024), dim3(TPB), 0, stream,
                       x_noisy, ws, out, n_iter);
}

// Round 10
// 308.972 us; speedup vs baseline: 1.6265x; 1.0777x over previous
//
#include <hip/hip_runtime.h>
#include <math.h>

#define F_ 48
#define C_ 128
#define HW 16384
#define SCALE_C 0.999f
#define TPB 256

typedef __attribute__((ext_vector_type(8))) short short8;
typedef __attribute__((ext_vector_type(4))) float floatx4;
typedef __attribute__((ext_vector_type(8))) _Float16 half8;
typedef __attribute__((ext_vector_type(4))) _Float16 half4;

// ---- ws layout ----
// ushort region:
//   P1 frags (f16, b-independent): [mt(12)][ks(4)][lane(64)][j(8)] = 24576 ushorts
//   P2 frags (bf16 hi/lo):   [b(2)][hl(2)][cmt(8)][ks(6)][lane(64)][j(8)] at 98304
// float region at float offset 98304 (byte 393216):
#define P1_U 0
#define P2_U 98304
#define QEQN_F 98304              // [48][32]
#define MISC_F (QEQN_F + 1536)    // eps_e, invden
#define SINV_F (MISC_F + 2)       // [2][48] 1/scaling
#define SLAM_F (SINV_F + 96)      // [2][48] lamb_e*scaling

// LDS strides; XS: 76 dwords/row == 12 mod 32; AS: 52 == 20 mod 32.
#define XS 152
#define AS 104
#define QS 36    // sQ row stride in floats (slot 32 carries invs)

__device__ __forceinline__ unsigned short f2bf(float f) {     // RTNE
    unsigned u = __float_as_uint(f);
    unsigned r = u + 0x7fffu + ((u >> 16) & 1u);
    return (unsigned short)(r >> 16);
}
__device__ __forceinline__ float bf2f(unsigned short h) {
    return __uint_as_float(((unsigned)h) << 16);
}

// ---------------- setup: math (1 block, tiny) ----------------
__global__ void setup_math(const float* __restrict__ sigma,
                           const float* __restrict__ Qp,
                           const float* __restrict__ taus_p,
                           const float* __restrict__ lamb,
                           const float* __restrict__ eps_om,
                           const float* __restrict__ mw1, const float* __restrict__ mb1,
                           const float* __restrict__ mw2, const float* __restrict__ mb2,
                           const float* __restrict__ mw3, const float* __restrict__ mb3,
                           float* __restrict__ wsf)
{
    const int tid = threadIdx.x;
    if (tid < F_) {
        const int f = tid;
        float Qm[4][4];
        for (int g = 0; g < 4; ++g) {
            float s = 0.f;
            for (int l = 0; l < 4; ++l) s += fabsf(Qp[f * 16 + g * 4 + l]);
            float d = fmaxf(s, 1.0f);
            for (int l = 0; l < 4; ++l) Qm[g][l] = Qp[f * 16 + g * 4 + l] / d;
        }
        double A[4][4];
        for (int i = 0; i < 4; ++i)
            for (int j = 0; j < 4; ++j) {
                double s = 0.0;
                for (int g = 0; g < 4; ++g) s += (double)Qm[g][i] * (double)Qm[g][j];
                A[i][j] = s;
            }
        double M[4][4];
        for (int i = 0; i < 4; ++i) for (int j = 0; j < 4; ++j) M[i][j] = A[i][j];
        for (int it = 0; it < 30; ++it) {
            double T[4][4]; double mx = 0.0;
            for (int i = 0; i < 4; ++i)
                for (int j = 0; j < 4; ++j) {
                    double s = 0.0;
                    for (int k = 0; k < 4; ++k) s += M[i][k] * M[k][j];
                    T[i][j] = s;
                    double a = fabs(s); if (a > mx) mx = a;
                }
            if (mx < 1e-300) break;
            double inv = 1.0 / mx;
            for (int i = 0; i < 4; ++i) for (int j = 0; j < 4; ++j) M[i][j] = T[i][j] * inv;
        }
        int jb = 0; double bn = -1.0;
        for (int j = 0; j < 4; ++j) {
            double nn = 0.0;
            for (int i = 0; i < 4; ++i) nn += M[i][j] * M[i][j];
            if (nn > bn) { bn = nn; jb = j; }
        }
        double v[4]; for (int i = 0; i < 4; ++i) v[i] = M[i][jb];
        double Av[4];
        for (int i = 0; i < 4; ++i) {
            double s = 0.0;
            for (int j = 0; j < 4; ++j) s += A[i][j] * v[j];
            Av[i] = s;
        }
        double vv = 0.0, vav = 0.0;
        for (int i = 0; i < 4; ++i) { vv += v[i] * v[i]; vav += v[i] * Av[i]; }
        float lamf = (float)((vv > 0.0) ? (vav / vv) : 0.0);
        float tau = expf(fmaxf(taus_p[f], 0.0f));
        float qsv = SCALE_C / tau;
        for (int l = 0; l < 4; ++l)
            for (int g = 0; g < 4; ++g)
                wsf[QEQN_F + f * 32 + l * 4 + g] = qsv * Qm[l][g] / lamf;
        for (int g = 0; g < 4; ++g)
            for (int l = 0; l < 4; ++l)
                wsf[QEQN_F + f * 32 + 16 + g * 4 + l] = SCALE_C * Qm[g][l];
    }
    if (tid >= 48 && tid < 50) {
        const int b = tid - 48;
        float lamb_e = expf(lamb[0]);
        float sg = sigma[b];
        float t = sg * 20.0f - 2.0f;
        float h1[F_], h2[F_];
        for (int j = 0; j < F_; ++j) h1[j] = fmaxf(t * mw1[j] + mb1[j], 0.0f);
        for (int j = 0; j < F_; ++j) {
            float s = mb2[j];
            for (int k = 0; k < F_; ++k) s += h1[k] * mw2[k * F_ + j];
            h2[j] = fmaxf(s, 0.0f);
        }
        for (int j = 0; j < F_; ++j) {
            float s = mb3[j];
            for (int k = 0; k < F_; ++k) s += h2[k] * mw3[k * F_ + j];
            float sc = fmaxf(s * 0.05f + sg, 0.0f) + 1e-9f;
            wsf[SINV_F + b * F_ + j] = 1.0f / sc;
            wsf[SLAM_F + b * F_ + j] = lamb_e * sc;
        }
    }
    if (tid == 50) {
        float lamb_e = expf(lamb[0]);
        float eps_e = expf(eps_om[0]);
        wsf[MISC_F + 0] = eps_e;
        wsf[MISC_F + 1] = 1.0f / (1.0f + lamb_e * (1.0f + eps_e));
    }
}

// ---------------- setup: fragment packing (grid-parallel) ----------------
__global__ void setup_pack(const float* __restrict__ Wf, float* __restrict__ wsf)
{
    unsigned short* wsu = (unsigned short*)wsf;
    const int gtid = blockIdx.x * TPB + threadIdx.x;
    for (int i = gtid; i < 49152; i += gridDim.x * TPB) {
        if (i < 24576) {
            // pass-1 A frags: f16 single, NO scaling fold (f16 range!)
            int j = i & 7, lane = (i >> 3) & 63;
            int t = i >> 9;                // 0..47
            int ks = t & 3, mt = t >> 2;
            int m = lane & 15, q = lane >> 4;
            int r = mt * 16 + m;
            int c = ks * 32 + q * 8 + j;
            int f = r >> 2, g = r & 3;
            float w = Wf[(g * F_ + f) * C_ + c];
            _Float16 hv = (_Float16)w;
            wsu[P1_U + ((mt * 4 + ks) * 64 + lane) * 8 + j] = *(unsigned short*)&hv;
        } else {
            // pass-2 A frags: bf16 hi/lo, fold lamb_e*scaling (unchanged)
            int ii = i - 24576;
            int j = ii & 7, lane = (ii >> 3) & 63;
            int t = ii >> 9;
            int ks = t % 6, cmt = t / 6;
            int m = lane & 15, q = lane >> 4;
            int cch = cmt * 16 + m;
            int r = ks * 32 + q * 8 + j;
            int f = r >> 2, g = r & 3;
            float w = Wf[(g * F_ + f) * C_ + cch];
#pragma unroll
            for (int b = 0; b < 2; ++b) {
                float v = w * wsf[SLAM_F + b * F_ + f];
                unsigned short h = (unsigned short)(__float_as_uint(v) >> 16);
                float lo = v - bf2f(h);
                unsigned short l = (unsigned short)(__float_as_uint(lo) >> 16);
                wsu[P2_U + ((((b * 2 + 0) * 8 + cmt) * 6 + ks) * 64 + lane) * 8 + j] = h;
                wsu[P2_U + ((((b * 2 + 1) * 8 + cmt) * 6 + ks) * 64 + lane) * 8 + j] = l;
            }
        }
    }
}

// Euclidean projection of a 4-vector onto the unit l1 ball (per lane, in regs)
__device__ __forceinline__ void proj4(const float v[4], float o[4]) {
    float a0 = fabsf(v[0]), a1 = fabsf(v[1]), a2 = fabsf(v[2]), a3 = fabsf(v[3]);
    float sum = a0 + a1 + a2 + a3;
    float t0 = fmaxf(a0, a1), u0 = fminf(a0, a1);
    float t1 = fmaxf(a2, a3), u1 = fminf(a2, a3);
    float s0 = fmaxf(t0, t1), m0 = fminf(t0, t1);
    float m1 = fmaxf(u0, u1), s3 = fminf(u0, u1);
    float s1 = fmaxf(m1, m0), s2 = fminf(m1, m0);
    float c2 = s0 + s1, c3 = c2 + s2, c4 = c3 + s3;
    float th = s0 - 1.0f, rh = 1.0f;
    if (s1 * 2.0f > c2 - 1.0f) { th = c2 - 1.0f; rh = 2.0f; }
    if (s2 * 3.0f > c3 - 1.0f) { th = c3 - 1.0f; rh = 3.0f; }
    if (s3 * 4.0f > c4 - 1.0f) { th = c4 - 1.0f; rh = 4.0f; }
    float theta = fmaxf(th / rh, 0.0f);
    bool inside = (sum <= 1.0f);
#pragma unroll
    for (int g = 0; g < 4; ++g) {
        float ag = fabsf(v[g]);
        float pg = copysignf(fmaxf(ag - theta, 0.0f), v[g]);
        o[g] = inside ? v[g] : pg;
    }
}

// ---------------- main: 32-pixel tile per block, 1024 blocks ----------------
__global__ __launch_bounds__(TPB, 4) void mfoe_main(
    const float* __restrict__ xnoisy,
    const float* __restrict__ wsf,
    float* __restrict__ out,
    const int* __restrict__ n_iter_p)
{
    __shared__ __align__(16) _Float16 sXF[32 * XS];
    __shared__ __align__(16) unsigned short sACT[32 * AS];
    __shared__ __align__(16) float sQ[F_ * QS];

    const int tid = threadIdx.x;
    const int lane = tid & 63;
    const int wv = __builtin_amdgcn_readfirstlane(tid >> 6);   // SGPR wave id
    const int n = lane & 15;
    const int q = lane >> 4;
    const int blk = blockIdx.x;
    const int b = blk >> 9;                 // 512 blocks per image
    const int pix0 = (blk & 511) << 5;      // 32 pixels per block

    const float* __restrict__ xin = xnoisy + b * (C_ * HW) + pix0;
    float* __restrict__ oimg = out + b * (C_ * HW) + pix0;
    const unsigned short* __restrict__ wsu = (const unsigned short*)wsf;
    const int niter = *n_iter_p;

    if (niter == 0) {
        for (int i = tid; i < C_ * 32; i += TPB) {
            int p = i & 31, c = i >> 5;
            oimg[c * HW + p] = xin[c * HW + p];
        }
        return;
    }

    // stage x -> LDS f16 (coalesced reads, single cvt per element)
    for (int i = tid; i < C_ * 32; i += TPB) {
        int p = i & 31, c = i >> 5;
        sXF[p * XS + c] = (_Float16)xin[c * HW + p];
    }
    // stage activation params -> LDS (padded rows); slot 32 = invs per f
    for (int i = tid; i < F_ * 32; i += TPB)
        sQ[(i >> 5) * QS + (i & 31)] = wsf[QEQN_F + i];
    for (int i = tid; i < F_; i += TPB)
        sQ[i * QS + 32] = wsf[SINV_F + b * F_ + i];

    // preload this thread's x_noisy values (update layout)
    float xnr[16];
#pragma unroll
    for (int j = 0; j < 4; ++j) {
        int jw = wv * 4 + j, cmt = jw >> 1, nt = jw & 1;
        int p = nt * 16 + n;
#pragma unroll
        for (int reg = 0; reg < 4; ++reg)
            xnr[j * 4 + reg] = xin[(cmt * 16 + q * 4 + reg) * HW + p];
    }
    const float eps_e = wsf[MISC_F + 0];
    const float invden = wsf[MISC_F + 1];

    for (int it = 0; it < niter; ++it) {
        floatx4 acc2[4];
#pragma unroll
        for (int j = 0; j < 4; ++j) acc2[j] = (floatx4){0.f, 0.f, 0.f, 0.f};

#pragma unroll 1
        for (int h = 0; h < 2; ++h) {
            __syncthreads();   // x ready / act buffer free
            // ---- pass 1: 12 (mtile,ntile) jobs per half, 3 per wave, f16 single
#pragma unroll 1
            for (int j = 0; j < 3; ++j) {
                int jw = wv * 3 + j, mtl = jw >> 1, nt = jw & 1;
                int mt = h * 6 + mtl;
                int p = nt * 16 + n;
                floatx4 acc = (floatx4){0.f, 0.f, 0.f, 0.f};
                const half8* aFp = (const half8*)(wsu + P1_U + (mt * 4) * 512 + lane * 8);
#pragma unroll
                for (int ks = 0; ks < 4; ++ks) {
                    half8 aF = aFp[ks * 64];
                    half8 bF = *(const half8*)&sXF[p * XS + ks * 32 + q * 8];
                    acc = __builtin_amdgcn_mfma_f32_16x16x32_f16(aF, bF, acc, 0, 0, 0);
                }
                // ---- activation in D-regs: lane owns (f, pixel p); apply invs here
                int f = h * 24 + mtl * 4 + q;
                float qv[32];
#pragma unroll
                for (int k = 0; k < 8; ++k)
                    *(floatx4*)&qv[4 * k] = *(const floatx4*)&sQ[f * QS + 4 * k];
                float invs = sQ[f * QS + 32];
                float v[4] = {acc[0] * invs, acc[1] * invs, acc[2] * invs, acc[3] * invs};
                float pv[4]; proj4(v, pv);
                float y[4];
#pragma unroll
                for (int l = 0; l < 4; ++l)
                    y[l] = fmaf(qv[l * 4 + 0], v[0], fmaf(qv[l * 4 + 1], v[1],
                           fmaf(qv[l * 4 + 2], v[2], qv[l * 4 + 3] * v[3])));
                float py[4]; proj4(y, py);
                float m2[4];
#pragma unroll
                for (int g = 0; g < 4; ++g) m2[g] = fmaf(eps_e, y[g], py[g]);
                unsigned pk0, pk1;
                {
                    float a0, a1;
                    float gcc0 = fmaf(qv[16 + 0], m2[0], fmaf(qv[16 + 4], m2[1],
                                 fmaf(qv[16 + 8], m2[2], qv[16 + 12] * m2[3])));
                    a0 = fmaf(eps_e, v[0], pv[0]) - gcc0;
                    float gcc1 = fmaf(qv[17 + 0], m2[0], fmaf(qv[17 + 4], m2[1],
                                 fmaf(qv[17 + 8], m2[2], qv[17 + 12] * m2[3])));
                    a1 = fmaf(eps_e, v[1], pv[1]) - gcc1;
                    pk0 = ((unsigned)f2bf(a1) << 16) | f2bf(a0);
                    float gcc2 = fmaf(qv[18 + 0], m2[0], fmaf(qv[18 + 4], m2[1],
                                 fmaf(qv[18 + 8], m2[2], qv[18 + 12] * m2[3])));
                    a0 = fmaf(eps_e, v[2], pv[2]) - gcc2;
                    float gcc3 = fmaf(qv[19 + 0], m2[0], fmaf(qv[19 + 4], m2[1],
                                 fmaf(qv[19 + 8], m2[2], qv[19 + 12] * m2[3])));
                    a1 = fmaf(eps_e, v[3], pv[3]) - gcc3;
                    pk1 = ((unsigned)f2bf(a1) << 16) | f2bf(a0);
                }
                unsigned long long pk = ((unsigned long long)pk1 << 32) | pk0;
                *(unsigned long long*)&sACT[p * AS + mtl * 16 + q * 4] = pk;
            }
            __syncthreads();   // act ready
            // ---- pass 2 partial: 16 (ctile,ntile) jobs, 4 per wave (bf16 unchanged)
#pragma unroll
            for (int j = 0; j < 4; ++j) {
                int jw = wv * 4 + j, cmt = jw >> 1, nt = jw & 1;
                int p = nt * 16 + n;
                const short8* a2H = (const short8*)(wsu + P2_U + (((b * 2 + 0) * 8 + cmt) * 6 + h * 3) * 512 + lane * 8);
                const short8* a2L = (const short8*)(wsu + P2_U + (((b * 2 + 1) * 8 + cmt) * 6 + h * 3) * 512 + lane * 8);
                floatx4 a = acc2[j];
#pragma unroll
                for (int ksl = 0; ksl < 3; ++ksl) {
                    short8 aH = a2H[ksl * 64];
                    short8 aL = a2L[ksl * 64];
                    short8 bA = *(const short8*)&sACT[p * AS + ksl * 32 + q * 8];
                    a = __builtin_amdgcn_mfma_f32_16x16x32_bf16(aH, bA, a, 0, 0, 0);
                    a = __builtin_amdgcn_mfma_f32_16x16x32_bf16(aL, bA, a, 0, 0, 0);
                }
                acc2[j] = a;
            }
        }
        // ---- update: thread owns (cmt,q,nt) cells; x kept as single f16
        const bool last = (it == niter - 1);
#pragma unroll
        for (int j = 0; j < 4; ++j) {
            int jw = wv * 4 + j, cmt = jw >> 1, nt = jw & 1;
            int p = nt * 16 + n;
            int cb = cmt * 16 + q * 4;
            half4 xo4 = *(const half4*)&sXF[p * XS + cb];
            float xo0 = (float)xo4[0];
            float xo1 = (float)xo4[1];
            float xo2 = (float)xo4[2];
            float xo3 = (float)xo4[3];
            float nx0 = xo0 - ((xo0 - xnr[j * 4 + 0]) + acc2[j][0]) * invden;
            float nx1 = xo1 - ((xo1 - xnr[j * 4 + 1]) + acc2[j][1]) * invden;
            float nx2 = xo2 - ((xo2 - xnr[j * 4 + 2]) + acc2[j][2]) * invden;
            float nx3 = xo3 - ((xo3 - xnr[j * 4 + 3]) + acc2[j][3]) * invden;
            if (last) {
                oimg[(cb + 0) * HW + p] = nx0;
                oimg[(cb + 1) * HW + p] = nx1;
                oimg[(cb + 2) * HW + p] = nx2;
                oimg[(cb + 3) * HW + p] = nx3;
            }
            half4 nx4;
            nx4[0] = (_Float16)nx0;
            nx4[1] = (_Float16)nx1;
            nx4[2] = (_Float16)nx2;
            nx4[3] = (_Float16)nx3;
            *(half4*)&sXF[p * XS + cb] = nx4;
        }
    }
}

extern "C" void kernel_launch(void* const* d_in, const int* in_sizes, int n_in,
                              void* d_out, int out_size, void* d_ws, size_t ws_size,
                              hipStream_t stream) {
    const float* x_noisy = (const float*)d_in[0];
    const float* sigma   = (const float*)d_in[1];
    const float* Qp      = (const float*)d_in[2];
    const float* taus_p  = (const float*)d_in[3];
    const float* lamb    = (const float*)d_in[4];
    const float* eps_om  = (const float*)d_in[5];
    const float* mw1     = (const float*)d_in[6];
    const float* mb1     = (const float*)d_in[7];
    const float* mw2     = (const float*)d_in[8];
    const float* mb2     = (const float*)d_in[9];
    const float* mw3     = (const float*)d_in[10];
    const float* mb3     = (const float*)d_in[11];
    const float* Wf      = (const float*)d_in[12];
    const int*   n_iter  = (const int*)d_in[13];
    float* out = (float*)d_out;
    float* ws  = (float*)d_ws;

    hipLaunchKernelGGL(setup_math, dim3(1), dim3(64), 0, stream,
                       sigma, Qp, taus_p, lamb, eps_om,
                       mw1, mb1, mw2, mb2, mw3, mb3, ws);
    hipLaunchKernelGGL(setup_pack, dim3(192), dim3(TPB), 0, stream, Wf, ws);
    hipLaunchKernelGGL(mfoe_main, dim3(1024), dim3(TPB), 0, stream,
                       x_noisy, ws, out, n_iter);
}

// Round 11
// 286.919 us; speedup vs baseline: 1.7516x; 1.0769x over previous
//
#include <hip/hip_runtime.h>
#include <math.h>

#define F_ 48
#define C_ 128
#define HW 16384
#define SCALE_C 0.999f
#define TPB 256

typedef __attribute__((ext_vector_type(8))) short short8;
typedef __attribute__((ext_vector_type(4))) float floatx4;
typedef __attribute__((ext_vector_type(8))) _Float16 half8;
typedef __attribute__((ext_vector_type(4))) _Float16 half4;

// ---- ws layout ----
// ushort region:
//   P1 frags (f16, b-independent): [mt(12)][ks(4)][lane(64)][j(8)] = 24576 ushorts
//   P2 frags (f16, b-independent): [cmt(8)][ks(6)][lane(64)][j(8)] = 24576 at 98304
// float region at float offset 98304 (byte 393216):
#define P1_U 0
#define P2_U 98304
#define QEQN_F 98304              // [48][32]
#define MISC_F (QEQN_F + 1536)    // eps_e, invden
#define SINV_F (MISC_F + 2)       // [2][48] 1/scaling
#define SLAM_F (SINV_F + 96)      // [2][48] lamb_e*scaling

// LDS strides; XS: 76 dwords/row == 12 mod 32; AS: 52 == 20 mod 32.
#define XS 152
#define AS 104
#define QS 36    // sQ row stride in floats (slot 32 = invs, slot 33 = slam)

__device__ __forceinline__ unsigned short f2bf(float f) {     // RTNE
    unsigned u = __float_as_uint(f);
    unsigned r = u + 0x7fffu + ((u >> 16) & 1u);
    return (unsigned short)(r >> 16);
}
__device__ __forceinline__ float bf2f(unsigned short h) {
    return __uint_as_float(((unsigned)h) << 16);
}

// ---------------- setup: math (1 block, tiny) ----------------
__global__ void setup_math(const float* __restrict__ sigma,
                           const float* __restrict__ Qp,
                           const float* __restrict__ taus_p,
                           const float* __restrict__ lamb,
                           const float* __restrict__ eps_om,
                           const float* __restrict__ mw1, const float* __restrict__ mb1,
                           const float* __restrict__ mw2, const float* __restrict__ mb2,
                           const float* __restrict__ mw3, const float* __restrict__ mb3,
                           float* __restrict__ wsf)
{
    const int tid = threadIdx.x;
    if (tid < F_) {
        const int f = tid;
        float Qm[4][4];
        for (int g = 0; g < 4; ++g) {
            float s = 0.f;
            for (int l = 0; l < 4; ++l) s += fabsf(Qp[f * 16 + g * 4 + l]);
            float d = fmaxf(s, 1.0f);
            for (int l = 0; l < 4; ++l) Qm[g][l] = Qp[f * 16 + g * 4 + l] / d;
        }
        double A[4][4];
        for (int i = 0; i < 4; ++i)
            for (int j = 0; j < 4; ++j) {
                double s = 0.0;
                for (int g = 0; g < 4; ++g) s += (double)Qm[g][i] * (double)Qm[g][j];
                A[i][j] = s;
            }
        double M[4][4];
        for (int i = 0; i < 4; ++i) for (int j = 0; j < 4; ++j) M[i][j] = A[i][j];
        for (int it = 0; it < 30; ++it) {
            double T[4][4]; double mx = 0.0;
            for (int i = 0; i < 4; ++i)
                for (int j = 0; j < 4; ++j) {
                    double s = 0.0;
                    for (int k = 0; k < 4; ++k) s += M[i][k] * M[k][j];
                    T[i][j] = s;
                    double a = fabs(s); if (a > mx) mx = a;
                }
            if (mx < 1e-300) break;
            double inv = 1.0 / mx;
            for (int i = 0; i < 4; ++i) for (int j = 0; j < 4; ++j) M[i][j] = T[i][j] * inv;
        }
        int jb = 0; double bn = -1.0;
        for (int j = 0; j < 4; ++j) {
            double nn = 0.0;
            for (int i = 0; i < 4; ++i) nn += M[i][j] * M[i][j];
            if (nn > bn) { bn = nn; jb = j; }
        }
        double v[4]; for (int i = 0; i < 4; ++i) v[i] = M[i][jb];
        double Av[4];
        for (int i = 0; i < 4; ++i) {
            double s = 0.0;
            for (int j = 0; j < 4; ++j) s += A[i][j] * v[j];
            Av[i] = s;
        }
        double vv = 0.0, vav = 0.0;
        for (int i = 0; i < 4; ++i) { vv += v[i] * v[i]; vav += v[i] * Av[i]; }
        float lamf = (float)((vv > 0.0) ? (vav / vv) : 0.0);
        float tau = expf(fmaxf(taus_p[f], 0.0f));
        float qsv = SCALE_C / tau;
        for (int l = 0; l < 4; ++l)
            for (int g = 0; g < 4; ++g)
                wsf[QEQN_F + f * 32 + l * 4 + g] = qsv * Qm[l][g] / lamf;
        for (int g = 0; g < 4; ++g)
            for (int l = 0; l < 4; ++l)
                wsf[QEQN_F + f * 32 + 16 + g * 4 + l] = SCALE_C * Qm[g][l];
    }
    if (tid >= 48 && tid < 50) {
        const int b = tid - 48;
        float lamb_e = expf(lamb[0]);
        float sg = sigma[b];
        float t = sg * 20.0f - 2.0f;
        float h1[F_], h2[F_];
        for (int j = 0; j < F_; ++j) h1[j] = fmaxf(t * mw1[j] + mb1[j], 0.0f);
        for (int j = 0; j < F_; ++j) {
            float s = mb2[j];
            for (int k = 0; k < F_; ++k) s += h1[k] * mw2[k * F_ + j];
            h2[j] = fmaxf(s, 0.0f);
        }
        for (int j = 0; j < F_; ++j) {
            float s = mb3[j];
            for (int k = 0; k < F_; ++k) s += h2[k] * mw3[k * F_ + j];
            float sc = fmaxf(s * 0.05f + sg, 0.0f) + 1e-9f;
            wsf[SINV_F + b * F_ + j] = 1.0f / sc;
            wsf[SLAM_F + b * F_ + j] = lamb_e * sc;
        }
    }
    if (tid == 50) {
        float lamb_e = expf(lamb[0]);
        float eps_e = expf(eps_om[0]);
        wsf[MISC_F + 0] = eps_e;
        wsf[MISC_F + 1] = 1.0f / (1.0f + lamb_e * (1.0f + eps_e));
    }
}

// ---------------- setup: fragment packing (grid-parallel) ----------------
__global__ void setup_pack(const float* __restrict__ Wf, float* __restrict__ wsf)
{
    unsigned short* wsu = (unsigned short*)wsf;
    const int gtid = blockIdx.x * TPB + threadIdx.x;
    for (int i = gtid; i < 49152; i += gridDim.x * TPB) {
        if (i < 24576) {
            // pass-1 A frags: f16 single, no fold (invs applied in-kernel)
            int j = i & 7, lane = (i >> 3) & 63;
            int t = i >> 9;                // 0..47
            int ks = t & 3, mt = t >> 2;
            int m = lane & 15, q = lane >> 4;
            int r = mt * 16 + m;
            int c = ks * 32 + q * 8 + j;
            int f = r >> 2, g = r & 3;
            float w = Wf[(g * F_ + f) * C_ + c];
            _Float16 hv = (_Float16)w;
            wsu[P1_U + ((mt * 4 + ks) * 64 + lane) * 8 + j] = *(unsigned short*)&hv;
        } else {
            // pass-2 A frags: f16 single, no fold (slam applied to act in-kernel)
            int ii = i - 24576;
            int j = ii & 7, lane = (ii >> 3) & 63;
            int t = ii >> 9;               // 0..47
            int ks = t % 6, cmt = t / 6;
            int m = lane & 15, q = lane >> 4;
            int cch = cmt * 16 + m;
            int r = ks * 32 + q * 8 + j;
            int g = r & 3;
            int f = r >> 2;
            float w = Wf[(g * F_ + f) * C_ + cch];
            _Float16 hv = (_Float16)w;
            wsu[P2_U + ((cmt * 6 + ks) * 64 + lane) * 8 + j] = *(unsigned short*)&hv;
        }
    }
}

// Euclidean projection of a 4-vector onto the unit l1 ball (per lane, in regs)
__device__ __forceinline__ void proj4(const float v[4], float o[4]) {
    float a0 = fabsf(v[0]), a1 = fabsf(v[1]), a2 = fabsf(v[2]), a3 = fabsf(v[3]);
    float sum = a0 + a1 + a2 + a3;
    float t0 = fmaxf(a0, a1), u0 = fminf(a0, a1);
    float t1 = fmaxf(a2, a3), u1 = fminf(a2, a3);
    float s0 = fmaxf(t0, t1), m0 = fminf(t0, t1);
    float m1 = fmaxf(u0, u1), s3 = fminf(u0, u1);
    float s1 = fmaxf(m1, m0), s2 = fminf(m1, m0);
    float c2 = s0 + s1, c3 = c2 + s2, c4 = c3 + s3;
    float th = s0 - 1.0f, rh = 1.0f;
    if (s1 * 2.0f > c2 - 1.0f) { th = c2 - 1.0f; rh = 2.0f; }
    if (s2 * 3.0f > c3 - 1.0f) { th = c3 - 1.0f; rh = 3.0f; }
    if (s3 * 4.0f > c4 - 1.0f) { th = c4 - 1.0f; rh = 4.0f; }
    float theta = fmaxf(th / rh, 0.0f);
    bool inside = (sum <= 1.0f);
#pragma unroll
    for (int g = 0; g < 4; ++g) {
        float ag = fabsf(v[g]);
        float pg = copysignf(fmaxf(ag - theta, 0.0f), v[g]);
        o[g] = inside ? v[g] : pg;
    }
}

// ---------------- main: 32-pixel tile per block, 1024 blocks ----------------
__global__ __launch_bounds__(TPB, 4) void mfoe_main(
    const float* __restrict__ xnoisy,
    const float* __restrict__ wsf,
    float* __restrict__ out,
    const int* __restrict__ n_iter_p)
{
    __shared__ __align__(16) _Float16 sXF[32 * XS];
    __shared__ __align__(16) _Float16 sACT[32 * AS];
    __shared__ __align__(16) float sQ[F_ * QS];

    const int tid = threadIdx.x;
    const int lane = tid & 63;
    const int wv = __builtin_amdgcn_readfirstlane(tid >> 6);   // SGPR wave id
    const int n = lane & 15;
    const int q = lane >> 4;
    const int blk = blockIdx.x;
    const int b = blk >> 9;                 // 512 blocks per image
    const int pix0 = (blk & 511) << 5;      // 32 pixels per block

    const float* __restrict__ xin = xnoisy + b * (C_ * HW) + pix0;
    float* __restrict__ oimg = out + b * (C_ * HW) + pix0;
    const unsigned short* __restrict__ wsu = (const unsigned short*)wsf;
    const int niter = *n_iter_p;

    if (niter == 0) {
        for (int i = tid; i < C_ * 32; i += TPB) {
            int p = i & 31, c = i >> 5;
            oimg[c * HW + p] = xin[c * HW + p];
        }
        return;
    }

    // stage x -> LDS f16 (coalesced reads, single cvt per element)
    for (int i = tid; i < C_ * 32; i += TPB) {
        int p = i & 31, c = i >> 5;
        sXF[p * XS + c] = (_Float16)xin[c * HW + p];
    }
    // stage activation params -> LDS (padded rows); slot 32 = invs, 33 = slam
    for (int i = tid; i < F_ * 32; i += TPB)
        sQ[(i >> 5) * QS + (i & 31)] = wsf[QEQN_F + i];
    for (int i = tid; i < F_; i += TPB) {
        sQ[i * QS + 32] = wsf[SINV_F + b * F_ + i];
        sQ[i * QS + 33] = wsf[SLAM_F + b * F_ + i];
    }

    // preload this thread's x_noisy values (update layout)
    float xnr[16];
#pragma unroll
    for (int j = 0; j < 4; ++j) {
        int jw = wv * 4 + j, cmt = jw >> 1, nt = jw & 1;
        int p = nt * 16 + n;
#pragma unroll
        for (int reg = 0; reg < 4; ++reg)
            xnr[j * 4 + reg] = xin[(cmt * 16 + q * 4 + reg) * HW + p];
    }
    const float eps_e = wsf[MISC_F + 0];
    const float invden = wsf[MISC_F + 1];

    for (int it = 0; it < niter; ++it) {
        floatx4 acc2[4];
#pragma unroll
        for (int j = 0; j < 4; ++j) acc2[j] = (floatx4){0.f, 0.f, 0.f, 0.f};

#pragma unroll 1
        for (int h = 0; h < 2; ++h) {
            __syncthreads();   // x ready / act buffer free
            // ---- pass 1: 12 (mtile,ntile) jobs per half, 3 per wave, f16 single
#pragma unroll 1
            for (int j = 0; j < 3; ++j) {
                int jw = wv * 3 + j, mtl = jw >> 1, nt = jw & 1;
                int mt = h * 6 + mtl;
                int p = nt * 16 + n;
                floatx4 acc = (floatx4){0.f, 0.f, 0.f, 0.f};
                const half8* aFp = (const half8*)(wsu + P1_U + (mt * 4) * 512 + lane * 8);
#pragma unroll
                for (int ks = 0; ks < 4; ++ks) {
                    half8 aF = aFp[ks * 64];
                    half8 bF = *(const half8*)&sXF[p * XS + ks * 32 + q * 8];
                    acc = __builtin_amdgcn_mfma_f32_16x16x32_f16(aF, bF, acc, 0, 0, 0);
                }
                // ---- activation in D-regs: lane owns (f, pixel p); apply invs here
                int f = h * 24 + mtl * 4 + q;
                float qv[32];
#pragma unroll
                for (int k = 0; k < 8; ++k)
                    *(floatx4*)&qv[4 * k] = *(const floatx4*)&sQ[f * QS + 4 * k];
                float invs = sQ[f * QS + 32];
                float slam = sQ[f * QS + 33];
                float v[4] = {acc[0] * invs, acc[1] * invs, acc[2] * invs, acc[3] * invs};
                float pv[4]; proj4(v, pv);
                float y[4];
#pragma unroll
                for (int l = 0; l < 4; ++l)
                    y[l] = fmaf(qv[l * 4 + 0], v[0], fmaf(qv[l * 4 + 1], v[1],
                           fmaf(qv[l * 4 + 2], v[2], qv[l * 4 + 3] * v[3])));
                float py[4]; proj4(y, py);
                float m2[4];
#pragma unroll
                for (int g = 0; g < 4; ++g) m2[g] = fmaf(eps_e, y[g], py[g]);
                // act scaled by slam = lamb_e*scaling -> O(0.1), f16-safe
                half4 av;
                {
                    float gcc0 = fmaf(qv[16 + 0], m2[0], fmaf(qv[16 + 4], m2[1],
                                 fmaf(qv[16 + 8], m2[2], qv[16 + 12] * m2[3])));
                    av[0] = (_Float16)((fmaf(eps_e, v[0], pv[0]) - gcc0) * slam);
                    float gcc1 = fmaf(qv[17 + 0], m2[0], fmaf(qv[17 + 4], m2[1],
                                 fmaf(qv[17 + 8], m2[2], qv[17 + 12] * m2[3])));
                    av[1] = (_Float16)((fmaf(eps_e, v[1], pv[1]) - gcc1) * slam);
                    float gcc2 = fmaf(qv[18 + 0], m2[0], fmaf(qv[18 + 4], m2[1],
                                 fmaf(qv[18 + 8], m2[2], qv[18 + 12] * m2[3])));
                    av[2] = (_Float16)((fmaf(eps_e, v[2], pv[2]) - gcc2) * slam);
                    float gcc3 = fmaf(qv[19 + 0], m2[0], fmaf(qv[19 + 4], m2[1],
                                 fmaf(qv[19 + 8], m2[2], qv[19 + 12] * m2[3])));
                    av[3] = (_Float16)((fmaf(eps_e, v[3], pv[3]) - gcc3) * slam);
                }
                *(half4*)&sACT[p * AS + mtl * 16 + q * 4] = av;
            }
            __syncthreads();   // act ready
            // ---- pass 2 partial: 16 (ctile,ntile) jobs, 4 per wave, f16 single
#pragma unroll
            for (int j = 0; j < 4; ++j) {
                int jw = wv * 4 + j, cmt = jw >> 1, nt = jw & 1;
                int p = nt * 16 + n;
                const half8* a2F = (const half8*)(wsu + P2_U + ((cmt * 6 + h * 3) * 64) * 8 + lane * 8);
                floatx4 a = acc2[j];
#pragma unroll
                for (int ksl = 0; ksl < 3; ++ksl) {
                    half8 aF = a2F[ksl * 64];
                    half8 bA = *(const half8*)&sACT[p * AS + ksl * 32 + q * 8];
                    a = __builtin_amdgcn_mfma_f32_16x16x32_f16(aF, bA, a, 0, 0, 0);
                }
                acc2[j] = a;
            }
        }
        // ---- update: thread owns (cmt,q,nt) cells; x kept as single f16
        const bool last = (it == niter - 1);
#pragma unroll
        for (int j = 0; j < 4; ++j) {
            int jw = wv * 4 + j, cmt = jw >> 1, nt = jw & 1;
            int p = nt * 16 + n;
            int cb = cmt * 16 + q * 4;
            half4 xo4 = *(const half4*)&sXF[p * XS + cb];
            float xo0 = (float)xo4[0];
            float xo1 = (float)xo4[1];
            float xo2 = (float)xo4[2];
            float xo3 = (float)xo4[3];
            float nx0 = xo0 - ((xo0 - xnr[j * 4 + 0]) + acc2[j][0]) * invden;
            float nx1 = xo1 - ((xo1 - xnr[j * 4 + 1]) + acc2[j][1]) * invden;
            float nx2 = xo2 - ((xo2 - xnr[j * 4 + 2]) + acc2[j][2]) * invden;
            float nx3 = xo3 - ((xo3 - xnr[j * 4 + 3]) + acc2[j][3]) * invden;
            if (last) {
                oimg[(cb + 0) * HW + p] = nx0;
                oimg[(cb + 1) * HW + p] = nx1;
                oimg[(cb + 2) * HW + p] = nx2;
                oimg[(cb + 3) * HW + p] = nx3;
            }
            half4 nx4;
            nx4[0] = (_Float16)nx0;
            nx4[1] = (_Float16)nx1;
            nx4[2] = (_Float16)nx2;
            nx4[3] = (_Float16)nx3;
            *(half4*)&sXF[p * XS + cb] = nx4;
        }
    }
}

extern "C" void kernel_launch(void* const* d_in, const int* in_sizes, int n_in,
                              void* d_out, int out_size, void* d_ws, size_t ws_size,
                              hipStream_t stream) {
    const float* x_noisy = (const float*)d_in[0];
    const float* sigma   = (const float*)d_in[1];
    const float* Qp      = (const float*)d_in[2];
    const float* taus_p  = (const float*)d_in[3];
    const float* lamb    = (const float*)d_in[4];
    const float* eps_om  = (const float*)d_in[5];
    const float* mw1     = (const float*)d_in[6];
    const float* mb1     = (const float*)d_in[7];
    const float* mw2     = (const float*)d_in[8];
    const float* mb2     = (const float*)d_in[9];
    const float* mw3     = (const float*)d_in[10];
    const float* mb3     = (const float*)d_in[11];
    const float* Wf      = (const float*)d_in[12];
    const int*   n_iter  = (const int*)d_in[13];
    float* out = (float*)d_out;
    float* ws  = (float*)d_ws;

    hipLaunchKernelGGL(setup_math, dim3(1), dim3(64), 0, stream,
                       sigma, Qp, taus_p, lamb, eps_om,
                       mw1, mb1, mw2, mb2, mw3, mb3, ws);
    hipLaunchKernelGGL(setup_pack, dim3(192), dim3(TPB), 0, stream, Wf, ws);
    hipLaunchKernelGGL(mfoe_main, dim3(1024), dim3(TPB), 0, stream,
                       x_noisy, ws, out, n_iter);
}

// Round 12
// 267.754 us; speedup vs baseline: 1.8769x; 1.0716x over previous
//
#include <hip/hip_runtime.h>
#include <math.h>

#define F_ 48
#define C_ 128
#define HW 16384
#define SCALE_C 0.999f
#define TPB 256      // setup kernels
#define MTPB 512     // main kernel: 8 waves/block

typedef __attribute__((ext_vector_type(8))) short short8;
typedef __attribute__((ext_vector_type(4))) float floatx4;
typedef __attribute__((ext_vector_type(8))) _Float16 half8;
typedef __attribute__((ext_vector_type(4))) _Float16 half4;

// ---- ws layout ----
// ushort region:
//   P1 frags (f16, b-independent): [mt(12)][ks(4)][lane(64)][j(8)] = 24576 ushorts
//   P2 frags (f16, b-independent): [cmt(8)][ks(6)][lane(64)][j(8)] = 24576 at 98304
// float region at float offset 98304 (byte 393216):
#define P1_U 0
#define P2_U 98304
#define QEQN_F 98304              // [48][32]
#define MISC_F (QEQN_F + 1536)    // eps_e, invden
#define SINV_F (MISC_F + 2)       // [2][48] 1/scaling
#define SLAM_F (SINV_F + 96)      // [2][48] lamb_e*scaling

// LDS strides; XS: 76 dwords/row == 12 mod 32; AS: 100 dwords == 4 mod 32.
#define XS 152
#define AS 200   // full 192 act rows + pad
#define QS 36    // sQ row stride in floats (slot 32 = invs, slot 33 = slam)

__device__ __forceinline__ unsigned short f2bf(float f) {     // RTNE
    unsigned u = __float_as_uint(f);
    unsigned r = u + 0x7fffu + ((u >> 16) & 1u);
    return (unsigned short)(r >> 16);
}
__device__ __forceinline__ float bf2f(unsigned short h) {
    return __uint_as_float(((unsigned)h) << 16);
}

// ---------------- setup: math (1 block, tiny) ----------------
__global__ void setup_math(const float* __restrict__ sigma,
                           const float* __restrict__ Qp,
                           const float* __restrict__ taus_p,
                           const float* __restrict__ lamb,
                           const float* __restrict__ eps_om,
                           const float* __restrict__ mw1, const float* __restrict__ mb1,
                           const float* __restrict__ mw2, const float* __restrict__ mb2,
                           const float* __restrict__ mw3, const float* __restrict__ mb3,
                           float* __restrict__ wsf)
{
    const int tid = threadIdx.x;
    if (tid < F_) {
        const int f = tid;
        float Qm[4][4];
        for (int g = 0; g < 4; ++g) {
            float s = 0.f;
            for (int l = 0; l < 4; ++l) s += fabsf(Qp[f * 16 + g * 4 + l]);
            float d = fmaxf(s, 1.0f);
            for (int l = 0; l < 4; ++l) Qm[g][l] = Qp[f * 16 + g * 4 + l] / d;
        }
        double A[4][4];
        for (int i = 0; i < 4; ++i)
            for (int j = 0; j < 4; ++j) {
                double s = 0.0;
                for (int g = 0; g < 4; ++g) s += (double)Qm[g][i] * (double)Qm[g][j];
                A[i][j] = s;
            }
        double M[4][4];
        for (int i = 0; i < 4; ++i) for (int j = 0; j < 4; ++j) M[i][j] = A[i][j];
        for (int it = 0; it < 30; ++it) {
            double T[4][4]; double mx = 0.0;
            for (int i = 0; i < 4; ++i)
                for (int j = 0; j < 4; ++j) {
                    double s = 0.0;
                    for (int k = 0; k < 4; ++k) s += M[i][k] * M[k][j];
                    T[i][j] = s;
                    double a = fabs(s); if (a > mx) mx = a;
                }
            if (mx < 1e-300) break;
            double inv = 1.0 / mx;
            for (int i = 0; i < 4; ++i) for (int j = 0; j < 4; ++j) M[i][j] = T[i][j] * inv;
        }
        int jb = 0; double bn = -1.0;
        for (int j = 0; j < 4; ++j) {
            double nn = 0.0;
            for (int i = 0; i < 4; ++i) nn += M[i][j] * M[i][j];
            if (nn > bn) { bn = nn; jb = j; }
        }
        double v[4]; for (int i = 0; i < 4; ++i) v[i] = M[i][jb];
        double Av[4];
        for (int i = 0; i < 4; ++i) {
            double s = 0.0;
            for (int j = 0; j < 4; ++j) s += A[i][j] * v[j];
            Av[i] = s;
        }
        double vv = 0.0, vav = 0.0;
        for (int i = 0; i < 4; ++i) { vv += v[i] * v[i]; vav += v[i] * Av[i]; }
        float lamf = (float)((vv > 0.0) ? (vav / vv) : 0.0);
        float tau = expf(fmaxf(taus_p[f], 0.0f));
        float qsv = SCALE_C / tau;
        for (int l = 0; l < 4; ++l)
            for (int g = 0; g < 4; ++g)
                wsf[QEQN_F + f * 32 + l * 4 + g] = qsv * Qm[l][g] / lamf;
        for (int g = 0; g < 4; ++g)
            for (int l = 0; l < 4; ++l)
                wsf[QEQN_F + f * 32 + 16 + g * 4 + l] = SCALE_C * Qm[g][l];
    }
    if (tid >= 48 && tid < 50) {
        const int b = tid - 48;
        float lamb_e = expf(lamb[0]);
        float sg = sigma[b];
        float t = sg * 20.0f - 2.0f;
        float h1[F_], h2[F_];
        for (int j = 0; j < F_; ++j) h1[j] = fmaxf(t * mw1[j] + mb1[j], 0.0f);
        for (int j = 0; j < F_; ++j) {
            float s = mb2[j];
            for (int k = 0; k < F_; ++k) s += h1[k] * mw2[k * F_ + j];
            h2[j] = fmaxf(s, 0.0f);
        }
        for (int j = 0; j < F_; ++j) {
            float s = mb3[j];
            for (int k = 0; k < F_; ++k) s += h2[k] * mw3[k * F_ + j];
            float sc = fmaxf(s * 0.05f + sg, 0.0f) + 1e-9f;
            wsf[SINV_F + b * F_ + j] = 1.0f / sc;
            wsf[SLAM_F + b * F_ + j] = lamb_e * sc;
        }
    }
    if (tid == 50) {
        float lamb_e = expf(lamb[0]);
        float eps_e = expf(eps_om[0]);
        wsf[MISC_F + 0] = eps_e;
        wsf[MISC_F + 1] = 1.0f / (1.0f + lamb_e * (1.0f + eps_e));
    }
}

// ---------------- setup: fragment packing (grid-parallel) ----------------
__global__ void setup_pack(const float* __restrict__ Wf, float* __restrict__ wsf)
{
    unsigned short* wsu = (unsigned short*)wsf;
    const int gtid = blockIdx.x * TPB + threadIdx.x;
    for (int i = gtid; i < 49152; i += gridDim.x * TPB) {
        if (i < 24576) {
            // pass-1 A frags: f16 single, no fold (invs applied in-kernel)
            int j = i & 7, lane = (i >> 3) & 63;
            int t = i >> 9;                // 0..47
            int ks = t & 3, mt = t >> 2;
            int m = lane & 15, q = lane >> 4;
            int r = mt * 16 + m;
            int c = ks * 32 + q * 8 + j;
            int f = r >> 2, g = r & 3;
            float w = Wf[(g * F_ + f) * C_ + c];
            _Float16 hv = (_Float16)w;
            wsu[P1_U + ((mt * 4 + ks) * 64 + lane) * 8 + j] = *(unsigned short*)&hv;
        } else {
            // pass-2 A frags: f16 single, no fold (slam applied to act in-kernel)
            int ii = i - 24576;
            int j = ii & 7, lane = (ii >> 3) & 63;
            int t = ii >> 9;               // 0..47
            int ks = t % 6, cmt = t / 6;
            int m = lane & 15, q = lane >> 4;
            int cch = cmt * 16 + m;
            int r = ks * 32 + q * 8 + j;
            int g = r & 3;
            int f = r >> 2;
            float w = Wf[(g * F_ + f) * C_ + cch];
            _Float16 hv = (_Float16)w;
            wsu[P2_U + ((cmt * 6 + ks) * 64 + lane) * 8 + j] = *(unsigned short*)&hv;
        }
    }
}

// Euclidean projection of a 4-vector onto the unit l1 ball (per lane, in regs)
__device__ __forceinline__ void proj4(const float v[4], float o[4]) {
    float a0 = fabsf(v[0]), a1 = fabsf(v[1]), a2 = fabsf(v[2]), a3 = fabsf(v[3]);
    float sum = a0 + a1 + a2 + a3;
    float t0 = fmaxf(a0, a1), u0 = fminf(a0, a1);
    float t1 = fmaxf(a2, a3), u1 = fminf(a2, a3);
    float s0 = fmaxf(t0, t1), m0 = fminf(t0, t1);
    float m1 = fmaxf(u0, u1), s3 = fminf(u0, u1);
    float s1 = fmaxf(m1, m0), s2 = fminf(m1, m0);
    float c2 = s0 + s1, c3 = c2 + s2, c4 = c3 + s3;
    float th = s0 - 1.0f, rh = 1.0f;
    if (s1 * 2.0f > c2 - 1.0f) { th = c2 - 1.0f; rh = 2.0f; }
    if (s2 * 3.0f > c3 - 1.0f) { th = c3 - 1.0f; rh = 3.0f; }
    if (s3 * 4.0f > c4 - 1.0f) { th = c4 - 1.0f; rh = 4.0f; }
    float theta = fmaxf(th / rh, 0.0f);
    bool inside = (sum <= 1.0f);
#pragma unroll
    for (int g = 0; g < 4; ++g) {
        float ag = fabsf(v[g]);
        float pg = copysignf(fmaxf(ag - theta, 0.0f), v[g]);
        o[g] = inside ? v[g] : pg;
    }
}

// ---------------- main: 32-pixel tile, 8 waves/block, full-K, 1024 blocks ----------------
__global__ __launch_bounds__(MTPB, 4) void mfoe_main(
    const float* __restrict__ xnoisy,
    const float* __restrict__ wsf,
    float* __restrict__ out,
    const int* __restrict__ n_iter_p)
{
    __shared__ __align__(16) _Float16 sXF[32 * XS];
    __shared__ __align__(16) _Float16 sACT[32 * AS];
    __shared__ __align__(16) float sQ[F_ * QS];

    const int tid = threadIdx.x;
    const int lane = tid & 63;
    const int wv = __builtin_amdgcn_readfirstlane(tid >> 6);   // SGPR wave id, 0..7
    const int n = lane & 15;
    const int q = lane >> 4;
    const int blk = blockIdx.x;
    const int b = blk >> 9;                 // 512 blocks per image
    const int pix0 = (blk & 511) << 5;      // 32 pixels per block

    const float* __restrict__ xin = xnoisy + b * (C_ * HW) + pix0;
    float* __restrict__ oimg = out + b * (C_ * HW) + pix0;
    const unsigned short* __restrict__ wsu = (const unsigned short*)wsf;
    const int niter = *n_iter_p;

    if (niter == 0) {
        for (int i = tid; i < C_ * 32; i += MTPB) {
            int p = i & 31, c = i >> 5;
            oimg[c * HW + p] = xin[c * HW + p];
        }
        return;
    }

    // stage x -> LDS f16 (coalesced reads, single cvt per element)
    for (int i = tid; i < C_ * 32; i += MTPB) {
        int p = i & 31, c = i >> 5;
        sXF[p * XS + c] = (_Float16)xin[c * HW + p];
    }
    // stage activation params -> LDS (padded rows); slot 32 = invs, 33 = slam
    for (int i = tid; i < F_ * 32; i += MTPB)
        sQ[(i >> 5) * QS + (i & 31)] = wsf[QEQN_F + i];
    for (int i = tid; i < F_; i += MTPB) {
        sQ[i * QS + 32] = wsf[SINV_F + b * F_ + i];
        sQ[i * QS + 33] = wsf[SLAM_F + b * F_ + i];
    }

    // preload this thread's x_noisy values (update layout): 2 jobs x 4 channels
    float xnr[8];
#pragma unroll
    for (int j = 0; j < 2; ++j) {
        int jw = wv * 2 + j, cmt = jw >> 1, nt = jw & 1;
        int p = nt * 16 + n;
#pragma unroll
        for (int reg = 0; reg < 4; ++reg)
            xnr[j * 4 + reg] = xin[(cmt * 16 + q * 4 + reg) * HW + p];
    }
    const float eps_e = wsf[MISC_F + 0];
    const float invden = wsf[MISC_F + 1];

    for (int it = 0; it < niter; ++it) {
        __syncthreads();   // x ready (and sQ on iter 0)
        // ---- pass 1: 24 (mt,nt) jobs, 3 per wave, f16 single
#pragma unroll 1
        for (int j = 0; j < 3; ++j) {
            int jw = wv * 3 + j, mt = jw >> 1, nt = jw & 1;
            int p = nt * 16 + n;
            floatx4 acc = (floatx4){0.f, 0.f, 0.f, 0.f};
            const half8* aFp = (const half8*)(wsu + P1_U + (mt * 4) * 512 + lane * 8);
#pragma unroll
            for (int ks = 0; ks < 4; ++ks) {
                half8 aF = aFp[ks * 64];
                half8 bF = *(const half8*)&sXF[p * XS + ks * 32 + q * 8];
                acc = __builtin_amdgcn_mfma_f32_16x16x32_f16(aF, bF, acc, 0, 0, 0);
            }
            // ---- activation in D-regs: lane owns (f, pixel p); apply invs here
            int f = mt * 4 + q;
            float qv[32];
#pragma unroll
            for (int k = 0; k < 8; ++k)
                *(floatx4*)&qv[4 * k] = *(const floatx4*)&sQ[f * QS + 4 * k];
            float invs = sQ[f * QS + 32];
            float slam = sQ[f * QS + 33];
            float v[4] = {acc[0] * invs, acc[1] * invs, acc[2] * invs, acc[3] * invs};
            float pv[4]; proj4(v, pv);
            float y[4];
#pragma unroll
            for (int l = 0; l < 4; ++l)
                y[l] = fmaf(qv[l * 4 + 0], v[0], fmaf(qv[l * 4 + 1], v[1],
                       fmaf(qv[l * 4 + 2], v[2], qv[l * 4 + 3] * v[3])));
            float py[4]; proj4(y, py);
            float m2[4];
#pragma unroll
            for (int g = 0; g < 4; ++g) m2[g] = fmaf(eps_e, y[g], py[g]);
            // act scaled by slam = lamb_e*scaling -> O(0.1), f16-safe
            half4 av;
            {
                float gcc0 = fmaf(qv[16 + 0], m2[0], fmaf(qv[16 + 4], m2[1],
                             fmaf(qv[16 + 8], m2[2], qv[16 + 12] * m2[3])));
                av[0] = (_Float16)((fmaf(eps_e, v[0], pv[0]) - gcc0) * slam);
                float gcc1 = fmaf(qv[17 + 0], m2[0], fmaf(qv[17 + 4], m2[1],
                             fmaf(qv[17 + 8], m2[2], qv[17 + 12] * m2[3])));
                av[1] = (_Float16)((fmaf(eps_e, v[1], pv[1]) - gcc1) * slam);
                float gcc2 = fmaf(qv[18 + 0], m2[0], fmaf(qv[18 + 4], m2[1],
                             fmaf(qv[18 + 8], m2[2], qv[18 + 12] * m2[3])));
                av[2] = (_Float16)((fmaf(eps_e, v[2], pv[2]) - gcc2) * slam);
                float gcc3 = fmaf(qv[19 + 0], m2[0], fmaf(qv[19 + 4], m2[1],
                             fmaf(qv[19 + 8], m2[2], qv[19 + 12] * m2[3])));
                av[3] = (_Float16)((fmaf(eps_e, v[3], pv[3]) - gcc3) * slam);
            }
            *(half4*)&sACT[p * AS + mt * 16 + q * 4] = av;
        }
        __syncthreads();   // act ready; all pass-1 x reads done
        // ---- pass 2: 16 (cmt,nt) jobs, 2 per wave, full K=192, f16 single
        floatx4 acc2[2];
#pragma unroll
        for (int j = 0; j < 2; ++j) acc2[j] = (floatx4){0.f, 0.f, 0.f, 0.f};
#pragma unroll
        for (int j = 0; j < 2; ++j) {
            int jw = wv * 2 + j, cmt = jw >> 1, nt = jw & 1;
            int p = nt * 16 + n;
            const half8* a2F = (const half8*)(wsu + P2_U + ((cmt * 6) * 64) * 8 + lane * 8);
            floatx4 a = acc2[j];
#pragma unroll
            for (int ks = 0; ks < 6; ++ks) {
                half8 aF = a2F[ks * 64];
                half8 bA = *(const half8*)&sACT[p * AS + ks * 32 + q * 8];
                a = __builtin_amdgcn_mfma_f32_16x16x32_f16(aF, bA, a, 0, 0, 0);
            }
            acc2[j] = a;
        }
        // ---- update: thread owns (cmt,q,nt) cells; x kept as single f16
        const bool last = (it == niter - 1);
#pragma unroll
        for (int j = 0; j < 2; ++j) {
            int jw = wv * 2 + j, cmt = jw >> 1, nt = jw & 1;
            int p = nt * 16 + n;
            int cb = cmt * 16 + q * 4;
            half4 xo4 = *(const half4*)&sXF[p * XS + cb];
            float xo0 = (float)xo4[0];
            float xo1 = (float)xo4[1];
            float xo2 = (float)xo4[2];
            float xo3 = (float)xo4[3];
            float nx0 = xo0 - ((xo0 - xnr[j * 4 + 0]) + acc2[j][0]) * invden;
            float nx1 = xo1 - ((xo1 - xnr[j * 4 + 1]) + acc2[j][1]) * invden;
            float nx2 = xo2 - ((xo2 - xnr[j * 4 + 2]) + acc2[j][2]) * invden;
            float nx3 = xo3 - ((xo3 - xnr[j * 4 + 3]) + acc2[j][3]) * invden;
            if (last) {
                oimg[(cb + 0) * HW + p] = nx0;
                oimg[(cb + 1) * HW + p] = nx1;
                oimg[(cb + 2) * HW + p] = nx2;
                oimg[(cb + 3) * HW + p] = nx3;
            }
            half4 nx4;
            nx4[0] = (_Float16)nx0;
            nx4[1] = (_Float16)nx1;
            nx4[2] = (_Float16)nx2;
            nx4[3] = (_Float16)nx3;
            *(half4*)&sXF[p * XS + cb] = nx4;
        }
    }
}

extern "C" void kernel_launch(void* const* d_in, const int* in_sizes, int n_in,
                              void* d_out, int out_size, void* d_ws, size_t ws_size,
                              hipStream_t stream) {
    const float* x_noisy = (const float*)d_in[0];
    const float* sigma   = (const float*)d_in[1];
    const float* Qp      = (const float*)d_in[2];
    const float* taus_p  = (const float*)d_in[3];
    const float* lamb    = (const float*)d_in[4];
    const float* eps_om  = (const float*)d_in[5];
    const float* mw1     = (const float*)d_in[6];
    const float* mb1     = (const float*)d_in[7];
    const float* mw2     = (const float*)d_in[8];
    const float* mb2     = (const float*)d_in[9];
    const float* mw3     = (const float*)d_in[10];
    const float* mb3     = (const float*)d_in[11];
    const float* Wf      = (const float*)d_in[12];
    const int*   n_iter  = (const int*)d_in[13];
    float* out = (float*)d_out;
    float* ws  = (float*)d_ws;

    hipLaunchKernelGGL(setup_math, dim3(1), dim3(64), 0, stream,
                       sigma, Qp, taus_p, lamb, eps_om,
                       mw1, mb1, mw2, mb2, mw3, mb3, ws);
    hipLaunchKernelGGL(setup_pack, dim3(192), dim3(TPB), 0, stream, Wf, ws);
    hipLaunchKernelGGL(mfoe_main, dim3(1024), dim3(MTPB), 0, stream,
                       x_noisy, ws, out, n_iter);
}